// Round 11
// baseline (249.321 us; speedup 1.0000x reference)
//
#include <hip/hip_runtime.h>
#include <cstdint>

#define D_MODEL 512
#define NUM_HEADS 8
#define D_HEAD 64
#define KNB 16
#define NBUCK 2048
#define LN_EPS 1e-5f
#define FINF 3.4e38f

typedef __bf16 bf16x8v __attribute__((ext_vector_type(8)));
typedef float f32x4v __attribute__((ext_vector_type(4)));
typedef int i32x4 __attribute__((ext_vector_type(4)));
typedef const __attribute__((address_space(1))) unsigned int* gptr_t;
typedef __attribute__((address_space(3))) unsigned int* lptr_t;

__device__ __forceinline__ float wave_reduce_sum(float v) {
  #pragma unroll
  for (int off = 32; off > 0; off >>= 1) v += __shfl_xor(v, off, 64);
  return v;
}

// bf16 helpers (bit-level, round-to-nearest-even)
__device__ __forceinline__ unsigned short f2bf(float x) {
  unsigned int u = __float_as_uint(x);
  u = (u + 0x7fffu + ((u >> 16) & 1u)) >> 16;
  return (unsigned short)u;
}
__device__ __forceinline__ float bf2f(unsigned short h) {
  return __uint_as_float(((unsigned int)h) << 16);
}

// Morton helpers: bucketing quality only affects SPEED.
__device__ __forceinline__ unsigned spread3(unsigned x) {
  x &= 0x3FFu;
  x = (x | (x << 16)) & 0x030000FFu;
  x = (x | (x << 8))  & 0x0300F00Fu;
  x = (x | (x << 4))  & 0x030C30C3u;
  x = (x | (x << 2))  & 0x09249249u;
  return x;
}
__device__ __forceinline__ unsigned quant10(float v) {
  int q = (int)((v + 6.f) * (1023.f / 12.f));
  q = q < 0 ? 0 : (q > 1023 ? 1023 : q);
  return (unsigned)q;
}

// 64-lane bitonic sort ascending by (d, j) lexicographic (pairs distinct).
__device__ __forceinline__ void bitonic64(float& d, int& j, int lane) {
  #pragma unroll
  for (int k = 2; k <= 64; k <<= 1) {
    #pragma unroll
    for (int s = k >> 1; s > 0; s >>= 1) {
      const float od = __shfl_xor(d, s, 64);
      const int   oj = __shfl_xor(j, s, 64);
      const bool up = ((lane & k) == 0);
      const bool lower = ((lane & s) == 0);
      const bool oless = (od < d) || (od == d && oj < j);
      if ((lower == up) ? oless : !oless) { d = od; j = oj; }
    }
  }
}

// ---------------------------------------------------------------------------
// Kernel 0a: zero bucket histogram
// ---------------------------------------------------------------------------
__global__ void zero_hist_kernel(int* __restrict__ hist, int n) {
  const int t = blockIdx.x * blockDim.x + threadIdx.x;
  if (t < n) hist[t] = 0;
}

// ---------------------------------------------------------------------------
// Kernel 0b: pad pos -> float4, Morton bucket (top 11 bits), histogram.
// ---------------------------------------------------------------------------
__global__ void bucket_kernel(const float* __restrict__ pos,
                              float4* __restrict__ posf4,
                              int* __restrict__ hist,
                              int* __restrict__ bucketid, int total) {
  const int t = blockIdx.x * blockDim.x + threadIdx.x;
  if (t >= total) return;
  const float4 p = make_float4(pos[t * 3], pos[t * 3 + 1], pos[t * 3 + 2], 0.f);
  posf4[t] = p;
  const unsigned code = (spread3(quant10(p.z)) << 2) |
                        (spread3(quant10(p.y)) << 1) | spread3(quant10(p.x));
  const int bk = code >> 19;
  const int b = t >> 12;
  bucketid[t] = bk;
  atomicAdd(&hist[b * NBUCK + bk], 1);
}

// ---------------------------------------------------------------------------
// Kernel 0c: exclusive scan of 2048 buckets per batch (one block per batch).
// ---------------------------------------------------------------------------
__global__ __launch_bounds__(1024) void scan_kernel(const int* __restrict__ hist,
                                                    int* __restrict__ off) {
  __shared__ int lsum[16];
  const int b = blockIdx.x;
  const int tid = threadIdx.x;
  const int lane = tid & 63, wv = tid >> 6;
  const int h0 = hist[b * NBUCK + 2 * tid];
  const int h1 = hist[b * NBUCK + 2 * tid + 1];
  int v = h0 + h1;
  #pragma unroll
  for (int d = 1; d < 64; d <<= 1) {
    const int u = __shfl_up(v, d, 64);
    if (lane >= d) v += u;
  }
  if (lane == 63) lsum[wv] = v;
  __syncthreads();
  if (wv == 0) {
    int s = (lane < 16) ? lsum[lane] : 0;
    #pragma unroll
    for (int d = 1; d < 16; d <<= 1) {
      const int u = __shfl_up(s, d, 64);
      if (lane >= d) s += u;
    }
    if (lane < 16) lsum[lane] = s;
  }
  __syncthreads();
  const int base = (wv > 0) ? lsum[wv - 1] : 0;
  const int excl = v + base - (h0 + h1);
  off[b * NBUCK + 2 * tid] = excl;
  off[b * NBUCK + 2 * tid + 1] = excl + h0;
}

// ---------------------------------------------------------------------------
// Kernel 0d: scatter into bucket order.
// ---------------------------------------------------------------------------
__global__ void scatter_kernel(const float4* __restrict__ posf4,
                               const int* __restrict__ bucketid,
                               int* __restrict__ off,
                               int* __restrict__ perm,
                               float4* __restrict__ posf4s, int total) {
  const int t = blockIdx.x * blockDim.x + threadIdx.x;
  if (t >= total) return;
  const int b = t >> 12;
  const int i = t & 4095;
  const int slot = atomicAdd(&off[b * NBUCK + bucketid[t]], 1);
  perm[b * 4096 + slot] = i;
  posf4s[b * 4096 + slot] = posf4[t];
}

// ---------------------------------------------------------------------------
// Kernel 1: kNN (proven round-4 version: 512 threads, float4 LDS, 72KB).
// ---------------------------------------------------------------------------
__global__ __launch_bounds__(512, 4) void knn_kernel(const float4* __restrict__ posf4s,
                                                     int* __restrict__ idx_out,
                                                     int N) {
  __shared__ float4 pts[4096];      // 64 KB: whole batch, staged once
  __shared__ float scrD[16 * 64];   // 4 KB: survivor distances (per query)
  __shared__ int   scrJ[16 * 64];   // 4 KB: survivor sorted-ids

  const int tid = threadIdx.x;
  const int lane = tid & 63;
  const int wid = tid >> 6;                 // 0..7
  const int qs0 = blockIdx.x * 16 + wid * 2;  // this wave's first query (sorted id)
  const int base = qs0 & ~4095;
  const int n0 = qs0 & 4095;                // batch-local sorted positions
  const int n1 = n0 + 1;
  const float4* pb = posf4s + base;

  // ---- stage the whole 4096-point batch into LDS (8 x 16B per thread) ----
  #pragma unroll
  for (int i = 0; i < 8; ++i) {
    const int c = wid * 8 + i;              // chunk 0..63, 64 points each
    __builtin_amdgcn_global_load_lds((gptr_t)(pb + c * 64 + lane),
                                     (lptr_t)&pts[c * 64], 16, 0, 0);
  }
  __syncthreads();

  const float4 qp0 = pts[n0];
  const float4 qp1 = pts[n1];

  // ---- scan (shared reads): per-lane minima for both queries ----
  float lmin0 = FINF, lmin1 = FINF;
  #pragma unroll 8
  for (int it = 0; it < 64; ++it) {
    const int j = (it << 6) + lane;
    const float4 p = pts[j];
    float dx = qp0.x - p.x, dy = qp0.y - p.y, dz = qp0.z - p.z;
    float d0 = dx * dx + dy * dy + dz * dz;
    dx = qp1.x - p.x; dy = qp1.y - p.y; dz = qp1.z - p.z;
    float d1 = dx * dx + dy * dy + dz * dz;
    if (j == n0) d0 = FINF;
    if (j == n1) d1 = FINF;
    lmin0 = fminf(lmin0, d0);
    lmin1 = fminf(lmin1, d1);
  }

  // ---- tau = 16th smallest lane-min (guarantees >=16 survivors).
  // Value-only bitonic, two queries interleaved for ILP. ----
  float a0 = lmin0, a1 = lmin1;
  #pragma unroll
  for (int k = 2; k <= 64; k <<= 1) {
    #pragma unroll
    for (int s = k >> 1; s > 0; s >>= 1) {
      const bool keepmin = (((lane & k) == 0) == ((lane & s) == 0));
      const float b0 = __shfl_xor(a0, s, 64);
      const float b1 = __shfl_xor(a1, s, 64);
      a0 = keepmin ? fminf(a0, b0) : fmaxf(a0, b0);
      a1 = keepmin ? fminf(a1, b1) : fmaxf(a1, b1);
    }
  }
  float tau0 = __shfl(a0, 15, 64);
  float tau1 = __shfl(a1, 15, 64);

  // ---- compaction (shared reads, recompute d): survivors -> LDS, cap 64 ----
  const unsigned long long lt = (1ull << lane) - 1ull;
  const int wq0 = wid * 2, wq1 = wid * 2 + 1;
  int cnt0 = 0, cnt1 = 0;
  #pragma unroll 4
  for (int it = 0; it < 64; ++it) {
    const int j = (it << 6) + lane;
    const float4 p = pts[j];
    float dx = qp0.x - p.x, dy = qp0.y - p.y, dz = qp0.z - p.z;
    float d0 = dx * dx + dy * dy + dz * dz;
    dx = qp1.x - p.x; dy = qp1.y - p.y; dz = qp1.z - p.z;
    float d1 = dx * dx + dy * dy + dz * dz;
    if (j == n0) d0 = FINF;
    if (j == n1) d1 = FINF;
    const bool p0 = (d0 <= tau0);
    const bool p1 = (d1 <= tau1);
    const unsigned long long m0 = __ballot(p0);
    const unsigned long long m1 = __ballot(p1);
    if (p0) {
      const int s0 = cnt0 + __popcll(m0 & lt);
      if (s0 < 64) { scrD[wq0 * 64 + s0] = d0; scrJ[wq0 * 64 + s0] = j; }
    }
    if (p1) {
      const int s1 = cnt1 + __popcll(m1 & lt);
      if (s1 < 64) { scrD[wq1 * 64 + s1] = d1; scrJ[wq1 * 64 + s1] = j; }
    }
    cnt0 += (int)__popcll(m0);
    cnt1 += (int)__popcll(m1);
  }

  // ---- per-query: sort survivors; rare retry tightens tau until cnt<=64 ----
  for (int q = 0; q < 2; ++q) {
    const int wq = wid * 2 + q;
    int cnt = q ? cnt1 : cnt0;
    float tau = q ? tau1 : tau0;
    const float4 qp = q ? qp1 : qp0;
    const int n = q ? n1 : n0;
    const int qs = qs0 + q;

    int m = cnt < 64 ? cnt : 64;
    float d = (lane < m) ? scrD[wq * 64 + lane] : FINF;
    int  jj = (lane < m) ? scrJ[wq * 64 + lane] : 0x40000000 + lane;
    bitonic64(d, jj, lane);

    while (cnt > 64) {
      // 16th smallest of 64 captured global elements -> valid tighter tau
      const float ntau = __shfl(d, 15, 64);
      if (!(ntau < tau)) break;   // degenerate exact-tie plateau: accept
      tau = ntau;
      cnt = 0;
      #pragma unroll 4
      for (int it = 0; it < 64; ++it) {
        const int j = (it << 6) + lane;
        const float4 p = pts[j];
        const float ddx = qp.x - p.x, ddy = qp.y - p.y, ddz = qp.z - p.z;
        float dd = ddx * ddx + ddy * ddy + ddz * ddz;
        if (j == n) dd = FINF;
        const bool pr = (dd <= tau);
        const unsigned long long mm = __ballot(pr);
        if (pr) {
          const int sl = cnt + __popcll(mm & lt);
          if (sl < 64) { scrD[wq * 64 + sl] = dd; scrJ[wq * 64 + sl] = j; }
        }
        cnt += (int)__popcll(mm);
      }
      m = cnt < 64 ? cnt : 64;
      d = (lane < m) ? scrD[wq * 64 + lane] : FINF;
      jj = (lane < m) ? scrJ[wq * 64 + lane] : 0x40000000 + lane;
      bitonic64(d, jj, lane);
    }

    if (lane < KNB) idx_out[(size_t)qs * KNB + lane] = jj;
  }
}

// ---------------------------------------------------------------------------
// Kernel 2: MERGED conv (feat + weights) — blockIdx-range fusion.
// ---------------------------------------------------------------------------
__global__ __launch_bounds__(256) void conv_kernel(const float* __restrict__ src,
                                                   const int* __restrict__ perm,
                                                   unsigned short* __restrict__ dst,
                                                   const float* __restrict__ Wq,
                                                   const float* __restrict__ Wk,
                                                   const float* __restrict__ Wv,
                                                   const float* __restrict__ Wo,
                                                   unsigned short* __restrict__ BhQKV,
                                                   unsigned short* __restrict__ BlQKV,
                                                   unsigned short* __restrict__ BhO,
                                                   unsigned short* __restrict__ BlO) {
  const int b = blockIdx.x;
  if (b < 4096) {
    const int t = b * 256 + threadIdx.x;
    const int f = t * 4;
    const int row = f >> 9;
    const int col = f & 511;
    const int orig = (row & ~4095) + perm[row];
    const float4 v = *(const float4*)(src + (size_t)orig * 512 + col);
    ushort4 h, l;
    h.x = f2bf(v.x); l.x = f2bf(v.x - bf2f(h.x));
    h.y = f2bf(v.y); l.y = f2bf(v.y - bf2f(h.y));
    h.z = f2bf(v.z); l.z = f2bf(v.z - bf2f(h.z));
    h.w = f2bf(v.w); l.w = f2bf(v.w - bf2f(h.w));
    *(ushort4*)(dst + (size_t)row * 1024 + col) = h;
    *(ushort4*)(dst + (size_t)row * 1024 + 512 + col) = l;
  } else {
    const int bb = b - 4096;
    const int wsel = bb >> 10;
    const int i = ((bb & 1023) << 8) + threadIdx.x;
    const int n = i >> 9;
    const int k = i & 511;
    const float* wsrc = wsel == 0 ? Wq : wsel == 1 ? Wk : wsel == 2 ? Wv : Wo;
    unsigned short* dh = wsel < 3 ? BhQKV + (size_t)(wsel * 512 + n) * 512
                                  : BhO + (size_t)n * 512;
    unsigned short* dl = wsel < 3 ? BlQKV + (size_t)(wsel * 512 + n) * 512
                                  : BlO + (size_t)n * 512;
    const float w = wsrc[(size_t)k * 512 + n];
    const unsigned short h = f2bf(w);
    dh[k] = h;
    dl[k] = f2bf(w - bf2f(h));
  }
}

// ---------------------------------------------------------------------------
// Kernel 3: split-bf16 MFMA GEMM — proven r20 LATENCY-HIDDEN schedule.
// ---------------------------------------------------------------------------
__global__ __launch_bounds__(256, 2) void gemm_split_kernel(
    const unsigned short* __restrict__ A,    // M x 1024  [hi|lo]
    const unsigned short* __restrict__ Bh,   // Ncols x 512
    const unsigned short* __restrict__ Bl,   // Ncols x 512
    float* __restrict__ C0, float* __restrict__ C1, float* __restrict__ C2,
    int nbn) {
  __shared__ unsigned short AsH[8192];   // 16 KB
  __shared__ unsigned short AsL[8192];   // 16 KB
  __shared__ unsigned short Bs[8192];    // 16 KB

  const int tid = threadIdx.x;
  const int wid = tid >> 6;
  const int lane = tid & 63;
  const int lm = lane & 15;
  const int kq = lane >> 4;
  const int wr = wid >> 1;
  const int wc = wid & 1;
  const int bid = blockIdx.x;
  const int xcd = bid & 7;
  const int i = bid >> 3;
  const int bm = xcd * 8 + i / nbn;
  const int bn = i % nbn;
  const int rowA0 = bm * 128;
  const int rowB0 = bn * 128;

  f32x4v acc[4][4];
  #pragma unroll
  for (int mi = 0; mi < 4; ++mi)
    #pragma unroll
    for (int ni = 0; ni < 4; ++ni) {
      f32x4v z = {0.f, 0.f, 0.f, 0.f};
      acc[mi][ni] = z;
    }

  auto stage64 = [&](unsigned short* dst, const unsigned short* gsrc,
                     int gstride, int grow0, int gk0) {
    #pragma unroll
    for (int i2 = 0; i2 < 4; ++i2) {
      const int c = wid * 256 + i2 * 64 + lane;   // chunk 0..1023
      const int row = c >> 3;
      const int gq = (c & 7) ^ (row & 7);
      const unsigned short* ga =
          gsrc + (size_t)(grow0 + row) * gstride + gk0 + gq * 8;
      __builtin_amdgcn_global_load_lds((gptr_t)ga,
          (lptr_t)(dst + (size_t)(wid * 256 + i2 * 64) * 8), 16, 0, 0);
    }
  };
  auto rd64 = [&](const unsigned short* src, int row, int g) -> i32x4 {
    const int sl = row * 8 + (g ^ (row & 7));
    return *(const i32x4*)(src + (size_t)sl * 8);
  };

  // ---- prologue: stage tile k0=0 for sweep 1 ----
  stage64(AsH, A, 1024, rowA0, 0);
  stage64(AsL, A, 1024, rowA0, 512);
  stage64(Bs, Bh, 512, rowB0, 0);

  // ---- sweep 1 (forward k): (Ah + Al) x Bh, 64 MFMA/tile ----
  for (int k0 = 0; k0 < 512; k0 += 64) {
    __syncthreads();   // (a) stage landed (drains vmcnt), LDS consistent
    i32x4 ah[2][4], al[2][4], bh[2][4];
    #pragma unroll
    for (int kh = 0; kh < 2; ++kh) {
      const int g = kh * 4 + kq;
      #pragma unroll
      for (int mi = 0; mi < 4; ++mi) {
        ah[kh][mi] = rd64(AsH, wr * 64 + mi * 16 + lm, g);
        al[kh][mi] = rd64(AsL, wr * 64 + mi * 16 + lm, g);
      }
      #pragma unroll
      for (int ni = 0; ni < 4; ++ni)
        bh[kh][ni] = rd64(Bs, wc * 64 + ni * 16 + lm, g);
    }
    __syncthreads();   // (b) all waves done reading LDS

    if (k0 < 448) {
      stage64(AsH, A, 1024, rowA0, k0 + 64);
      stage64(AsL, A, 1024, rowA0, 512 + k0 + 64);
      stage64(Bs, Bh, 512, rowB0, k0 + 64);
    } else {
      // sweep-2 tile 0 (k=448) reuses resident AsH; only Bl needed.
      stage64(Bs, Bl, 512, rowB0, 448);
    }

    #pragma unroll
    for (int kh = 0; kh < 2; ++kh)
      #pragma unroll
      for (int mi = 0; mi < 4; ++mi)
        #pragma unroll
        for (int ni = 0; ni < 4; ++ni) {
          acc[mi][ni] = __builtin_amdgcn_mfma_f32_16x16x32_bf16(
              __builtin_bit_cast(bf16x8v, ah[kh][mi]),
              __builtin_bit_cast(bf16x8v, bh[kh][ni]), acc[mi][ni], 0, 0, 0);
          acc[mi][ni] = __builtin_amdgcn_mfma_f32_16x16x32_bf16(
              __builtin_bit_cast(bf16x8v, al[kh][mi]),
              __builtin_bit_cast(bf16x8v, bh[kh][ni]), acc[mi][ni], 0, 0, 0);
        }
  }

  // ---- sweep 2 (reverse k): Ah x Bl, 32 MFMA/tile ----
  for (int k0 = 448; k0 >= 0; k0 -= 64) {
    __syncthreads();   // (a) stage landed
    i32x4 ah[2][4], bl[2][4];
    #pragma unroll
    for (int kh = 0; kh < 2; ++kh) {
      const int g = kh * 4 + kq;
      #pragma unroll
      for (int mi = 0; mi < 4; ++mi)
        ah[kh][mi] = rd64(AsH, wr * 64 + mi * 16 + lm, g);
      #pragma unroll
      for (int ni = 0; ni < 4; ++ni)
        bl[kh][ni] = rd64(Bs, wc * 64 + ni * 16 + lm, g);
    }
    __syncthreads();   // (b) LDS free

    if (k0 > 0) {
      stage64(AsH, A, 1024, rowA0, k0 - 64);
      stage64(Bs, Bl, 512, rowB0, k0 - 64);
    }

    #pragma unroll
    for (int kh = 0; kh < 2; ++kh)
      #pragma unroll
      for (int mi = 0; mi < 4; ++mi)
        #pragma unroll
        for (int ni = 0; ni < 4; ++ni)
          acc[mi][ni] = __builtin_amdgcn_mfma_f32_16x16x32_bf16(
              __builtin_bit_cast(bf16x8v, ah[kh][mi]),
              __builtin_bit_cast(bf16x8v, bl[kh][ni]), acc[mi][ni], 0, 0, 0);
  }

  const int sel = bn >> 2;
  float* __restrict__ Cb = sel == 0 ? C0 : sel == 1 ? C1 : C2;
  const int r0 = bm * 128 + wr * 64;
  const int c0 = ((bn & 3) << 7) + wc * 64;
  // C/D layout: col = lane&15, row = (lane>>4)*4 + reg   [m89/m91]
  #pragma unroll
  for (int mi = 0; mi < 4; ++mi)
    #pragma unroll
    for (int ni = 0; ni < 4; ++ni) {
      float* Cp = Cb + (size_t)(r0 + mi * 16 + kq * 4) * 512 + c0 + ni * 16 + lm;
      #pragma unroll
      for (int r = 0; r < 4; ++r) Cp[(size_t)r * 512] = acc[mi][ni][r];
    }
}

// ---------------------------------------------------------------------------
// Kernel 4: local attention — 2 WAVES PER QUERY, FIXED per-head merge.
// r10 post-mortem: heads live in 8-lane groups (group = lane>>3); m/ssum are
// per-GROUP values (8 per wave), not wave-uniform. The r9/r10 merge stored
// only lane 0's stats (head 0) and applied them to all heads -> absmax 2.07.
// Fix: mS/sS are [wave][head]; group leader (lane&7)==0 writes index
// lane>>3; merge reads per-group. Everything else unchanged.
// ---------------------------------------------------------------------------
__global__ __launch_bounds__(256) void attn_kernel(const float* __restrict__ Q,
                                                   const float* __restrict__ Kb,
                                                   const float* __restrict__ Vb,
                                                   const int* __restrict__ idx,
                                                   const float4* __restrict__ posf4s,
                                                   const float* __restrict__ Wpos,
                                                   const float* __restrict__ bpos,
                                                   const float* __restrict__ temperature,
                                                   unsigned short* __restrict__ Aout,
                                                   int nblocks) {
  __shared__ float mS[4][8], sS[4][8];
  __shared__ float accHalf[2][512];   // half-B partial V-acc per query

  int bid = blockIdx.x;
  bid = (bid & 7) * (nblocks >> 3) + (bid >> 3);        // XCD-contiguous
  const int wid = threadIdx.x >> 6;
  const int lane = threadIdx.x & 63;
  const int qi = wid >> 1;            // query within block (0..1)
  const int hf = wid & 1;             // neighbor half (0..1)
  const int qs = bid * 2 + qi;
  const int s = lane & 7;
  const int grp = lane >> 3;          // head group (0..7)
  const int base = qs & ~4095;

  const float inv_t = 1.0f / temperature[0];

  float q[8];
  *(float4*)&q[0] = *(const float4*)(Q + (size_t)qs * D_MODEL + lane * 8);
  *(float4*)&q[4] = *(const float4*)(Q + (size_t)qs * D_MODEL + lane * 8 + 4);

  float wp[3][8], bp[8];
  #pragma unroll
  for (int c = 0; c < 3; ++c) {
    *(float4*)&wp[c][0] = *(const float4*)(Wpos + c * 128 + s * 8);
    *(float4*)&wp[c][4] = *(const float4*)(Wpos + c * 128 + s * 8 + 4);
  }
  *(float4*)&bp[0] = *(const float4*)(bpos + s * 8);
  *(float4*)&bp[4] = *(const float4*)(bpos + s * 8 + 4);
  float qw0 = 0.f, qw1 = 0.f, qw2 = 0.f, qb = 0.f;
  #pragma unroll
  for (int j = 0; j < 8; ++j) {
    qw0 += q[j] * wp[0][j];
    qw1 += q[j] * wp[1][j];
    qw2 += q[j] * wp[2][j];
    qb  += q[j] * bp[j];
  }
  #pragma unroll
  for (int off = 1; off < 8; off <<= 1) {
    qw0 += __shfl_xor(qw0, off, 64);
    qw1 += __shfl_xor(qw1, off, 64);
    qw2 += __shfl_xor(qw2, off, 64);
    qb  += __shfl_xor(qb, off, 64);
  }

  const float4 qp = posf4s[qs];
  const int* ip = idx + (size_t)qs * KNB + hf * 8;
  int nb[8];
  #pragma unroll
  for (int k = 0; k < 8; ++k) nb[k] = base + ip[k];   // sorted row

  // ---- pe: this half's 8 neighbor positions in flight at once ----
  float pe[8];
  {
    float4 np[8];
    #pragma unroll
    for (int k = 0; k < 8; ++k) np[k] = posf4s[nb[k]];
    #pragma unroll
    for (int k = 0; k < 8; ++k)
      pe[k] = qw0 * (qp.x - np[k].x) + qw1 * (qp.y - np[k].y) +
              qw2 * (qp.z - np[k].z) + qb;
  }

  // ---- scores: one batch of 8 K-rows, 16 float4 loads in flight ----
  float sc[8];
  {
    float kk[8][8];
    #pragma unroll
    for (int k = 0; k < 8; ++k) {
      const float* kr = Kb + (size_t)nb[k] * D_MODEL + lane * 8;
      *(float4*)&kk[k][0] = *(const float4*)(kr);
      *(float4*)&kk[k][4] = *(const float4*)(kr + 4);
    }
    #pragma unroll
    for (int k = 0; k < 8; ++k) {
      float pdot = 0.f;
      #pragma unroll
      for (int j2 = 0; j2 < 8; ++j2) pdot += q[j2] * kk[k][j2];
      #pragma unroll
      for (int off = 1; off < 8; off <<= 1) pdot += __shfl_xor(pdot, off, 64);
      sc[k] = (pdot + pe[k]) * inv_t;
    }
  }

  // ---- local softmax (this half, per head group) ----
  float m = sc[0];
  #pragma unroll
  for (int k = 1; k < 8; ++k) m = fmaxf(m, sc[k]);
  float ssum = 0.f;
  #pragma unroll
  for (int k = 0; k < 8; ++k) { sc[k] = expf(sc[k] - m); ssum += sc[k]; }

  // ---- local weighted V: one batch of 8 rows ----
  float acc[8];
  #pragma unroll
  for (int j = 0; j < 8; ++j) acc[j] = 0.f;
  {
    float vv[8][8];
    #pragma unroll
    for (int k = 0; k < 8; ++k) {
      const float* vr = Vb + (size_t)nb[k] * D_MODEL + lane * 8;
      *(float4*)&vv[k][0] = *(const float4*)(vr);
      *(float4*)&vv[k][4] = *(const float4*)(vr + 4);
    }
    #pragma unroll
    for (int k = 0; k < 8; ++k) {
      const float wk = sc[k];
      #pragma unroll
      for (int j = 0; j < 8; ++j) acc[j] += wk * vv[k][j];
    }
  }

  // ---- 2-way online-softmax merge via LDS (PER HEAD GROUP) ----
  if ((lane & 7) == 0) { mS[wid][grp] = m; sS[wid][grp] = ssum; }
  if (hf == 1) {
    #pragma unroll
    for (int j = 0; j < 8; ++j) accHalf[qi][j * 64 + lane] = acc[j];
  }
  __syncthreads();
  if (hf == 0) {
    const float mB = mS[wid + 1][grp];
    const float sB = sS[wid + 1][grp];
    const float M = fmaxf(m, mB);
    const float wA = expf(m - M);
    const float wB = expf(mB - M);
    const float inv_s = 1.f / (ssum * wA + sB * wB);

    float a[8];
    #pragma unroll
    for (int j = 0; j < 8; ++j)
      a[j] = (acc[j] * wA + accHalf[qi][j * 64 + lane] * wB) * inv_s;

    ushort4 hi0, hi1, lo0, lo1;
    unsigned short* oh = Aout + (size_t)qs * 1024 + lane * 8;
    unsigned short* ol = oh + 512;
    hi0.x = f2bf(a[0]); lo0.x = f2bf(a[0] - bf2f(hi0.x));
    hi0.y = f2bf(a[1]); lo0.y = f2bf(a[1] - bf2f(hi0.y));
    hi0.z = f2bf(a[2]); lo0.z = f2bf(a[2] - bf2f(hi0.z));
    hi0.w = f2bf(a[3]); lo0.w = f2bf(a[3] - bf2f(hi0.w));
    hi1.x = f2bf(a[4]); lo1.x = f2bf(a[4] - bf2f(hi1.x));
    hi1.y = f2bf(a[5]); lo1.y = f2bf(a[5] - bf2f(hi1.y));
    hi1.z = f2bf(a[6]); lo1.z = f2bf(a[6] - bf2f(hi1.z));
    hi1.w = f2bf(a[7]); lo1.w = f2bf(a[7] - bf2f(hi1.w));
    *(ushort4*)(oh) = hi0;
    *(ushort4*)(oh + 4) = hi1;
    *(ushort4*)(ol) = lo0;
    *(ushort4*)(ol + 4) = lo1;
  }
}

// ---------------------------------------------------------------------------
// Kernel 5: LN over sorted proj rows, un-permuting on the final write.
// ---------------------------------------------------------------------------
__global__ __launch_bounds__(256) void ln_kernel(const float* __restrict__ proj,
                                                 const float* __restrict__ feat,
                                                 const int* __restrict__ perm,
                                                 const float* __restrict__ bo,
                                                 const float* __restrict__ gamma,
                                                 const float* __restrict__ beta,
                                                 float* __restrict__ out) {
  const int row = blockIdx.x * 4 + (threadIdx.x >> 6);
  const int lane = threadIdx.x & 63;
  const int orig = (row & ~4095) + perm[row];
  const float* pr = proj + (size_t)row * D_MODEL;
  const float* fr = feat + (size_t)orig * D_MODEL;

  float x[8];
  #pragma unroll
  for (int u = 0; u < 2; ++u) {
    const int c = u * 256 + lane * 4;
    const float4 p = *(const float4*)(pr + c);
    const float4 f = *(const float4*)(fr + c);
    const float4 bb = *(const float4*)(bo + c);
    x[u * 4 + 0] = p.x + bb.x + f.x;
    x[u * 4 + 1] = p.y + bb.y + f.y;
    x[u * 4 + 2] = p.z + bb.z + f.z;
    x[u * 4 + 3] = p.w + bb.w + f.w;
  }
  float sum = 0.f, sumsq = 0.f;
  #pragma unroll
  for (int i = 0; i < 8; ++i) { sum += x[i]; sumsq += x[i] * x[i]; }
  sum = wave_reduce_sum(sum);
  sumsq = wave_reduce_sum(sumsq);
  const float mu = sum * (1.f / D_MODEL);
  const float var = sumsq * (1.f / D_MODEL) - mu * mu;
  const float rstd = rsqrtf(var + LN_EPS);

  #pragma unroll
  for (int u = 0; u < 2; ++u) {
    const int c = u * 256 + lane * 4;
    const float4 g = *(const float4*)(gamma + c);
    const float4 bt = *(const float4*)(beta + c);
    float4 o;
    o.x = (x[u * 4 + 0] - mu) * rstd * g.x + bt.x;
    o.y = (x[u * 4 + 1] - mu) * rstd * g.y + bt.y;
    o.z = (x[u * 4 + 2] - mu) * rstd * g.z + bt.z;
    o.w = (x[u * 4 + 3] - mu) * rstd * g.w + bt.w;
    *(float4*)(out + (size_t)orig * D_MODEL + c) = o;
  }
}

// ---------------------------------------------------------------------------
extern "C" void kernel_launch(void* const* d_in, const int* in_sizes, int n_in,
                              void* d_out, int out_size, void* d_ws, size_t ws_size,
                              hipStream_t stream) {
  const float* positions = (const float*)d_in[0];
  const float* features  = (const float*)d_in[1];
  const float* Wq   = (const float*)d_in[3];
  const float* Wk   = (const float*)d_in[4];
  const float* Wv   = (const float*)d_in[5];
  const float* Wo   = (const float*)d_in[6];
  const float* bo   = (const float*)d_in[7];
  const float* Wpos = (const float*)d_in[8];
  const float* bpos = (const float*)d_in[9];
  const float* temp = (const float*)d_in[10];
  const float* gamma = (const float*)d_in[11];
  const float* beta  = (const float*)d_in[12];

  const int B = 2, N = 4096;
  const int BN = B * N;

  char* w = (char*)d_ws;
  float4* posf4  = (float4*)w;             w += (size_t)BN * sizeof(float4);
  float4* posf4s = (float4*)w;             w += (size_t)BN * sizeof(float4);
  int*    idxb   = (int*)w;                w += (size_t)BN * KNB * sizeof(int);
  int*    permb  = (int*)w;                w += (size_t)BN * sizeof(int);
  int*    histb  = (int*)w;                w += (size_t)B * NBUCK * sizeof(int);
  int*    offb   = (int*)w;                w += (size_t)B * NBUCK * sizeof(int);
  int*    buckb  = (int*)w;                w += (size_t)BN * sizeof(int);
  unsigned short* Abuf = (unsigned short*)w; w += (size_t)BN * 1024 * 2;
  unsigned short* BhQKV = (unsigned short*)w; w += (size_t)1536 * 512 * 2;
  unsigned short* BlQKV = (unsigned short*)w; w += (size_t)1536 * 512 * 2;
  unsigned short* BhO = (unsigned short*)w;   w += (size_t)512 * 512 * 2;
  unsigned short* BlO = (unsigned short*)w;   w += (size_t)512 * 512 * 2;
  float* Qb   = (float*)w;                 w += (size_t)BN * D_MODEL * sizeof(float);
  float* Kbuf = (float*)w;                 w += (size_t)BN * D_MODEL * sizeof(float);
  float* Vbuf = (float*)d_out;             // dead before LN overwrites d_out
  float* projb = Kbuf;                     // K dead after attention

  zero_hist_kernel<<<(B * NBUCK + 255) / 256, 256, 0, stream>>>(histb, B * NBUCK);
  bucket_kernel<<<(BN + 255) / 256, 256, 0, stream>>>(positions, posf4, histb,
                                                      buckb, BN);
  scan_kernel<<<B, 1024, 0, stream>>>(histb, offb);
  scatter_kernel<<<(BN + 255) / 256, 256, 0, stream>>>(posf4, buckb, offb,
                                                       permb, posf4s, BN);
  knn_kernel<<<BN / 16, 512, 0, stream>>>(posf4s, idxb, N);

  conv_kernel<<<8192, 256, 0, stream>>>(features, permb, Abuf,
                                        Wq, Wk, Wv, Wo,
                                        BhQKV, BlQKV, BhO, BlO);

  gemm_split_kernel<<<768, 256, 0, stream>>>(
      Abuf, BhQKV, BlQKV, Qb, Kbuf, Vbuf, 12);

  attn_kernel<<<BN / 2, 256, 0, stream>>>(Qb, Kbuf, Vbuf, idxb,
                                          posf4s, Wpos, bpos, temp, Abuf,
                                          BN / 2);

  gemm_split_kernel<<<256, 256, 0, stream>>>(
      Abuf, BhO, BlO, projb, projb, projb, 4);

  ln_kernel<<<BN / 4, 256, 0, stream>>>(projb, features, permb, bo, gamma, beta,
                                        (float*)d_out);
}

// Round 12
// 211.915 us; speedup vs baseline: 1.1765x; 1.1765x over previous
//
#include <hip/hip_runtime.h>
#include <cstdint>

#define D_MODEL 512
#define NUM_HEADS 8
#define D_HEAD 64
#define KNB 16
#define NBUCK 2048
#define LN_EPS 1e-5f
#define FINF 3.4e38f

typedef __bf16 bf16x8v __attribute__((ext_vector_type(8)));
typedef float f32x4v __attribute__((ext_vector_type(4)));
typedef int i32x4 __attribute__((ext_vector_type(4)));
typedef const __attribute__((address_space(1))) unsigned int* gptr_t;
typedef __attribute__((address_space(3))) unsigned int* lptr_t;

__device__ __forceinline__ float wave_reduce_sum(float v) {
  #pragma unroll
  for (int off = 32; off > 0; off >>= 1) v += __shfl_xor(v, off, 64);
  return v;
}

// bf16 helpers (bit-level, round-to-nearest-even)
__device__ __forceinline__ unsigned short f2bf(float x) {
  unsigned int u = __float_as_uint(x);
  u = (u + 0x7fffu + ((u >> 16) & 1u)) >> 16;
  return (unsigned short)u;
}
__device__ __forceinline__ float bf2f(unsigned short h) {
  return __uint_as_float(((unsigned int)h) << 16);
}

// Morton helpers: bucketing quality only affects SPEED.
__device__ __forceinline__ unsigned spread3(unsigned x) {
  x &= 0x3FFu;
  x = (x | (x << 16)) & 0x030000FFu;
  x = (x | (x << 8))  & 0x0300F00Fu;
  x = (x | (x << 4))  & 0x030C30C3u;
  x = (x | (x << 2))  & 0x09249249u;
  return x;
}
__device__ __forceinline__ unsigned quant10(float v) {
  int q = (int)((v + 6.f) * (1023.f / 12.f));
  q = q < 0 ? 0 : (q > 1023 ? 1023 : q);
  return (unsigned)q;
}

// 64-lane bitonic sort ascending by (d, j) lexicographic (pairs distinct).
__device__ __forceinline__ void bitonic64(float& d, int& j, int lane) {
  #pragma unroll
  for (int k = 2; k <= 64; k <<= 1) {
    #pragma unroll
    for (int s = k >> 1; s > 0; s >>= 1) {
      const float od = __shfl_xor(d, s, 64);
      const int   oj = __shfl_xor(j, s, 64);
      const bool up = ((lane & k) == 0);
      const bool lower = ((lane & s) == 0);
      const bool oless = (od < d) || (od == d && oj < j);
      if ((lower == up) ? oless : !oless) { d = od; j = oj; }
    }
  }
}

// ---------------------------------------------------------------------------
// Kernel 0a: zero bucket histogram
// ---------------------------------------------------------------------------
__global__ void zero_hist_kernel(int* __restrict__ hist, int n) {
  const int t = blockIdx.x * blockDim.x + threadIdx.x;
  if (t < n) hist[t] = 0;
}

// ---------------------------------------------------------------------------
// Kernel 0b: pad pos -> float4, Morton bucket (top 11 bits), histogram.
// ---------------------------------------------------------------------------
__global__ void bucket_kernel(const float* __restrict__ pos,
                              float4* __restrict__ posf4,
                              int* __restrict__ hist,
                              int* __restrict__ bucketid, int total) {
  const int t = blockIdx.x * blockDim.x + threadIdx.x;
  if (t >= total) return;
  const float4 p = make_float4(pos[t * 3], pos[t * 3 + 1], pos[t * 3 + 2], 0.f);
  posf4[t] = p;
  const unsigned code = (spread3(quant10(p.z)) << 2) |
                        (spread3(quant10(p.y)) << 1) | spread3(quant10(p.x));
  const int bk = code >> 19;
  const int b = t >> 12;
  bucketid[t] = bk;
  atomicAdd(&hist[b * NBUCK + bk], 1);
}

// ---------------------------------------------------------------------------
// Kernel 0c: exclusive scan of 2048 buckets per batch (one block per batch).
// ---------------------------------------------------------------------------
__global__ __launch_bounds__(1024) void scan_kernel(const int* __restrict__ hist,
                                                    int* __restrict__ off) {
  __shared__ int lsum[16];
  const int b = blockIdx.x;
  const int tid = threadIdx.x;
  const int lane = tid & 63, wv = tid >> 6;
  const int h0 = hist[b * NBUCK + 2 * tid];
  const int h1 = hist[b * NBUCK + 2 * tid + 1];
  int v = h0 + h1;
  #pragma unroll
  for (int d = 1; d < 64; d <<= 1) {
    const int u = __shfl_up(v, d, 64);
    if (lane >= d) v += u;
  }
  if (lane == 63) lsum[wv] = v;
  __syncthreads();
  if (wv == 0) {
    int s = (lane < 16) ? lsum[lane] : 0;
    #pragma unroll
    for (int d = 1; d < 16; d <<= 1) {
      const int u = __shfl_up(s, d, 64);
      if (lane >= d) s += u;
    }
    if (lane < 16) lsum[lane] = s;
  }
  __syncthreads();
  const int base = (wv > 0) ? lsum[wv - 1] : 0;
  const int excl = v + base - (h0 + h1);
  off[b * NBUCK + 2 * tid] = excl;
  off[b * NBUCK + 2 * tid + 1] = excl + h0;
}

// ---------------------------------------------------------------------------
// Kernel 0d: scatter into bucket order.
// ---------------------------------------------------------------------------
__global__ void scatter_kernel(const float4* __restrict__ posf4,
                               const int* __restrict__ bucketid,
                               int* __restrict__ off,
                               int* __restrict__ perm,
                               float4* __restrict__ posf4s, int total) {
  const int t = blockIdx.x * blockDim.x + threadIdx.x;
  if (t >= total) return;
  const int b = t >> 12;
  const int i = t & 4095;
  const int slot = atomicAdd(&off[b * NBUCK + bucketid[t]], 1);
  perm[b * 4096 + slot] = i;
  posf4s[b * 4096 + slot] = posf4[t];
}

// ---------------------------------------------------------------------------
// Kernel 1: kNN (proven round-4 version: 512 threads, float4 LDS, 72KB).
// ---------------------------------------------------------------------------
__global__ __launch_bounds__(512, 4) void knn_kernel(const float4* __restrict__ posf4s,
                                                     int* __restrict__ idx_out,
                                                     int N) {
  __shared__ float4 pts[4096];      // 64 KB: whole batch, staged once
  __shared__ float scrD[16 * 64];   // 4 KB: survivor distances (per query)
  __shared__ int   scrJ[16 * 64];   // 4 KB: survivor sorted-ids

  const int tid = threadIdx.x;
  const int lane = tid & 63;
  const int wid = tid >> 6;                 // 0..7
  const int qs0 = blockIdx.x * 16 + wid * 2;  // this wave's first query (sorted id)
  const int base = qs0 & ~4095;
  const int n0 = qs0 & 4095;                // batch-local sorted positions
  const int n1 = n0 + 1;
  const float4* pb = posf4s + base;

  // ---- stage the whole 4096-point batch into LDS (8 x 16B per thread) ----
  #pragma unroll
  for (int i = 0; i < 8; ++i) {
    const int c = wid * 8 + i;              // chunk 0..63, 64 points each
    __builtin_amdgcn_global_load_lds((gptr_t)(pb + c * 64 + lane),
                                     (lptr_t)&pts[c * 64], 16, 0, 0);
  }
  __syncthreads();

  const float4 qp0 = pts[n0];
  const float4 qp1 = pts[n1];

  // ---- scan (shared reads): per-lane minima for both queries ----
  float lmin0 = FINF, lmin1 = FINF;
  #pragma unroll 8
  for (int it = 0; it < 64; ++it) {
    const int j = (it << 6) + lane;
    const float4 p = pts[j];
    float dx = qp0.x - p.x, dy = qp0.y - p.y, dz = qp0.z - p.z;
    float d0 = dx * dx + dy * dy + dz * dz;
    dx = qp1.x - p.x; dy = qp1.y - p.y; dz = qp1.z - p.z;
    float d1 = dx * dx + dy * dy + dz * dz;
    if (j == n0) d0 = FINF;
    if (j == n1) d1 = FINF;
    lmin0 = fminf(lmin0, d0);
    lmin1 = fminf(lmin1, d1);
  }

  // ---- tau = 16th smallest lane-min (guarantees >=16 survivors).
  // Value-only bitonic, two queries interleaved for ILP. ----
  float a0 = lmin0, a1 = lmin1;
  #pragma unroll
  for (int k = 2; k <= 64; k <<= 1) {
    #pragma unroll
    for (int s = k >> 1; s > 0; s >>= 1) {
      const bool keepmin = (((lane & k) == 0) == ((lane & s) == 0));
      const float b0 = __shfl_xor(a0, s, 64);
      const float b1 = __shfl_xor(a1, s, 64);
      a0 = keepmin ? fminf(a0, b0) : fmaxf(a0, b0);
      a1 = keepmin ? fminf(a1, b1) : fmaxf(a1, b1);
    }
  }
  float tau0 = __shfl(a0, 15, 64);
  float tau1 = __shfl(a1, 15, 64);

  // ---- compaction (shared reads, recompute d): survivors -> LDS, cap 64 ----
  const unsigned long long lt = (1ull << lane) - 1ull;
  const int wq0 = wid * 2, wq1 = wid * 2 + 1;
  int cnt0 = 0, cnt1 = 0;
  #pragma unroll 4
  for (int it = 0; it < 64; ++it) {
    const int j = (it << 6) + lane;
    const float4 p = pts[j];
    float dx = qp0.x - p.x, dy = qp0.y - p.y, dz = qp0.z - p.z;
    float d0 = dx * dx + dy * dy + dz * dz;
    dx = qp1.x - p.x; dy = qp1.y - p.y; dz = qp1.z - p.z;
    float d1 = dx * dx + dy * dy + dz * dz;
    if (j == n0) d0 = FINF;
    if (j == n1) d1 = FINF;
    const bool p0 = (d0 <= tau0);
    const bool p1 = (d1 <= tau1);
    const unsigned long long m0 = __ballot(p0);
    const unsigned long long m1 = __ballot(p1);
    if (p0) {
      const int s0 = cnt0 + __popcll(m0 & lt);
      if (s0 < 64) { scrD[wq0 * 64 + s0] = d0; scrJ[wq0 * 64 + s0] = j; }
    }
    if (p1) {
      const int s1 = cnt1 + __popcll(m1 & lt);
      if (s1 < 64) { scrD[wq1 * 64 + s1] = d1; scrJ[wq1 * 64 + s1] = j; }
    }
    cnt0 += (int)__popcll(m0);
    cnt1 += (int)__popcll(m1);
  }

  // ---- per-query: sort survivors; rare retry tightens tau until cnt<=64 ----
  for (int q = 0; q < 2; ++q) {
    const int wq = wid * 2 + q;
    int cnt = q ? cnt1 : cnt0;
    float tau = q ? tau1 : tau0;
    const float4 qp = q ? qp1 : qp0;
    const int n = q ? n1 : n0;
    const int qs = qs0 + q;

    int m = cnt < 64 ? cnt : 64;
    float d = (lane < m) ? scrD[wq * 64 + lane] : FINF;
    int  jj = (lane < m) ? scrJ[wq * 64 + lane] : 0x40000000 + lane;
    bitonic64(d, jj, lane);

    while (cnt > 64) {
      // 16th smallest of 64 captured global elements -> valid tighter tau
      const float ntau = __shfl(d, 15, 64);
      if (!(ntau < tau)) break;   // degenerate exact-tie plateau: accept
      tau = ntau;
      cnt = 0;
      #pragma unroll 4
      for (int it = 0; it < 64; ++it) {
        const int j = (it << 6) + lane;
        const float4 p = pts[j];
        const float ddx = qp.x - p.x, ddy = qp.y - p.y, ddz = qp.z - p.z;
        float dd = ddx * ddx + ddy * ddy + ddz * ddz;
        if (j == n) dd = FINF;
        const bool pr = (dd <= tau);
        const unsigned long long mm = __ballot(pr);
        if (pr) {
          const int sl = cnt + __popcll(mm & lt);
          if (sl < 64) { scrD[wq * 64 + sl] = dd; scrJ[wq * 64 + sl] = j; }
        }
        cnt += (int)__popcll(mm);
      }
      m = cnt < 64 ? cnt : 64;
      d = (lane < m) ? scrD[wq * 64 + lane] : FINF;
      jj = (lane < m) ? scrJ[wq * 64 + lane] : 0x40000000 + lane;
      bitonic64(d, jj, lane);
    }

    if (lane < KNB) idx_out[(size_t)qs * KNB + lane] = jj;
  }
}

// ---------------------------------------------------------------------------
// Kernel 2: MERGED conv (feat + weights) — Round 12: BF16-ONLY (no lo
// planes). Error budget: input-quantization-only GEMM adds ~0.02-0.03 max
// end-to-end (threshold 0.108, current 0.0156). Halves conv writes, A reads.
//   b < 4096:  features -> A bf16 Mx512, rows in sorted order
//   b >= 4096: weights (512x512 fp32, W[k][n]) -> transposed bf16
// ---------------------------------------------------------------------------
__global__ __launch_bounds__(256) void conv_kernel(const float* __restrict__ src,
                                                   const int* __restrict__ perm,
                                                   unsigned short* __restrict__ dst,
                                                   const float* __restrict__ Wq,
                                                   const float* __restrict__ Wk,
                                                   const float* __restrict__ Wv,
                                                   const float* __restrict__ Wo,
                                                   unsigned short* __restrict__ BhQKV,
                                                   unsigned short* __restrict__ BhO) {
  const int b = blockIdx.x;
  if (b < 4096) {
    const int t = b * 256 + threadIdx.x;
    const int f = t * 4;
    const int row = f >> 9;
    const int col = f & 511;
    const int orig = (row & ~4095) + perm[row];
    const float4 v = *(const float4*)(src + (size_t)orig * 512 + col);
    ushort4 h;
    h.x = f2bf(v.x);
    h.y = f2bf(v.y);
    h.z = f2bf(v.z);
    h.w = f2bf(v.w);
    *(ushort4*)(dst + (size_t)row * 512 + col) = h;
  } else {
    const int bb = b - 4096;
    const int wsel = bb >> 10;
    const int i = ((bb & 1023) << 8) + threadIdx.x;
    const int n = i >> 9;
    const int k = i & 511;
    const float* wsrc = wsel == 0 ? Wq : wsel == 1 ? Wk : wsel == 2 ? Wv : Wo;
    unsigned short* dh = wsel < 3 ? BhQKV + (size_t)(wsel * 512 + n) * 512
                                  : BhO + (size_t)n * 512;
    dh[k] = f2bf(wsrc[(size_t)k * 512 + n]);
  }
}

// ---------------------------------------------------------------------------
// Kernel 3: bf16 MFMA GEMM — Round 12: single product (A x B), r20
// latency-hidden schedule. LDS 32KB (As+Bs) -> 4-5 blocks/CU.
// Per tile: read frags -> barrier -> issue next stage -> 32 MFMA.
// ---------------------------------------------------------------------------
__global__ __launch_bounds__(256, 2) void gemm_bf16_kernel(
    const unsigned short* __restrict__ A,    // M x 512 bf16
    const unsigned short* __restrict__ B,    // Ncols x 512 bf16
    float* __restrict__ C0, float* __restrict__ C1, float* __restrict__ C2,
    int nbn) {
  __shared__ unsigned short As[8192];   // 128 rows x 64 halves (16 KB)
  __shared__ unsigned short Bs[8192];   // 16 KB

  const int tid = threadIdx.x;
  const int wid = tid >> 6;
  const int lane = tid & 63;
  const int lm = lane & 15;
  const int kq = lane >> 4;
  const int wr = wid >> 1;
  const int wc = wid & 1;
  const int bid = blockIdx.x;
  const int xcd = bid & 7;
  const int i = bid >> 3;
  const int bm = xcd * 8 + i / nbn;
  const int bn = i % nbn;
  const int rowA0 = bm * 128;
  const int rowB0 = bn * 128;

  f32x4v acc[4][4];
  #pragma unroll
  for (int mi = 0; mi < 4; ++mi)
    #pragma unroll
    for (int ni = 0; ni < 4; ++ni) {
      f32x4v z = {0.f, 0.f, 0.f, 0.f};
      acc[mi][ni] = z;
    }

  auto stage64 = [&](unsigned short* dst, const unsigned short* gsrc,
                     int grow0, int gk0) {
    #pragma unroll
    for (int i2 = 0; i2 < 4; ++i2) {
      const int c = wid * 256 + i2 * 64 + lane;   // chunk 0..1023
      const int row = c >> 3;
      const int gq = (c & 7) ^ (row & 7);
      const unsigned short* ga =
          gsrc + (size_t)(grow0 + row) * 512 + gk0 + gq * 8;
      __builtin_amdgcn_global_load_lds((gptr_t)ga,
          (lptr_t)(dst + (size_t)(wid * 256 + i2 * 64) * 8), 16, 0, 0);
    }
  };
  auto rd64 = [&](const unsigned short* src, int row, int g) -> i32x4 {
    const int sl = row * 8 + (g ^ (row & 7));
    return *(const i32x4*)(src + (size_t)sl * 8);
  };

  // ---- prologue: stage tile k0=0 ----
  stage64(As, A, rowA0, 0);
  stage64(Bs, B, rowB0, 0);

  for (int k0 = 0; k0 < 512; k0 += 64) {
    __syncthreads();   // (a) stage landed (drains vmcnt), LDS consistent
    i32x4 ah[2][4], bb[2][4];
    #pragma unroll
    for (int kh = 0; kh < 2; ++kh) {
      const int g = kh * 4 + kq;
      #pragma unroll
      for (int mi = 0; mi < 4; ++mi)
        ah[kh][mi] = rd64(As, wr * 64 + mi * 16 + lm, g);
      #pragma unroll
      for (int ni = 0; ni < 4; ++ni)
        bb[kh][ni] = rd64(Bs, wc * 64 + ni * 16 + lm, g);
    }
    __syncthreads();   // (b) all waves done reading LDS

    if (k0 < 448) {
      stage64(As, A, rowA0, k0 + 64);
      stage64(Bs, B, rowB0, k0 + 64);
    }

    #pragma unroll
    for (int kh = 0; kh < 2; ++kh)
      #pragma unroll
      for (int mi = 0; mi < 4; ++mi)
        #pragma unroll
        for (int ni = 0; ni < 4; ++ni)
          acc[mi][ni] = __builtin_amdgcn_mfma_f32_16x16x32_bf16(
              __builtin_bit_cast(bf16x8v, ah[kh][mi]),
              __builtin_bit_cast(bf16x8v, bb[kh][ni]), acc[mi][ni], 0, 0, 0);
  }

  const int sel = bn >> 2;
  float* __restrict__ Cb = sel == 0 ? C0 : sel == 1 ? C1 : C2;
  const int r0 = bm * 128 + wr * 64;
  const int c0 = ((bn & 3) << 7) + wc * 64;
  // C/D layout: col = lane&15, row = (lane>>4)*4 + reg   [m89/m91]
  #pragma unroll
  for (int mi = 0; mi < 4; ++mi)
    #pragma unroll
    for (int ni = 0; ni < 4; ++ni) {
      float* Cp = Cb + (size_t)(r0 + mi * 16 + kq * 4) * 512 + c0 + ni * 16 + lm;
      #pragma unroll
      for (int r = 0; r < 4; ++r) Cp[(size_t)r * 512] = acc[mi][ni][r];
    }
}

// ---------------------------------------------------------------------------
// Kernel 4: local attention — 2 waves/query, per-head merge (r11 verified).
// Round 12: Aout is bf16 hi-only (Mx512).
// ---------------------------------------------------------------------------
__global__ __launch_bounds__(256) void attn_kernel(const float* __restrict__ Q,
                                                   const float* __restrict__ Kb,
                                                   const float* __restrict__ Vb,
                                                   const int* __restrict__ idx,
                                                   const float4* __restrict__ posf4s,
                                                   const float* __restrict__ Wpos,
                                                   const float* __restrict__ bpos,
                                                   const float* __restrict__ temperature,
                                                   unsigned short* __restrict__ Aout,
                                                   int nblocks) {
  __shared__ float mS[4][8], sS[4][8];
  __shared__ float accHalf[2][512];   // half-B partial V-acc per query

  int bid = blockIdx.x;
  bid = (bid & 7) * (nblocks >> 3) + (bid >> 3);        // XCD-contiguous
  const int wid = threadIdx.x >> 6;
  const int lane = threadIdx.x & 63;
  const int qi = wid >> 1;            // query within block (0..1)
  const int hf = wid & 1;             // neighbor half (0..1)
  const int qs = bid * 2 + qi;
  const int s = lane & 7;
  const int grp = lane >> 3;          // head group (0..7)
  const int base = qs & ~4095;

  const float inv_t = 1.0f / temperature[0];

  float q[8];
  *(float4*)&q[0] = *(const float4*)(Q + (size_t)qs * D_MODEL + lane * 8);
  *(float4*)&q[4] = *(const float4*)(Q + (size_t)qs * D_MODEL + lane * 8 + 4);

  float wp[3][8], bp[8];
  #pragma unroll
  for (int c = 0; c < 3; ++c) {
    *(float4*)&wp[c][0] = *(const float4*)(Wpos + c * 128 + s * 8);
    *(float4*)&wp[c][4] = *(const float4*)(Wpos + c * 128 + s * 8 + 4);
  }
  *(float4*)&bp[0] = *(const float4*)(bpos + s * 8);
  *(float4*)&bp[4] = *(const float4*)(bpos + s * 8 + 4);
  float qw0 = 0.f, qw1 = 0.f, qw2 = 0.f, qb = 0.f;
  #pragma unroll
  for (int j = 0; j < 8; ++j) {
    qw0 += q[j] * wp[0][j];
    qw1 += q[j] * wp[1][j];
    qw2 += q[j] * wp[2][j];
    qb  += q[j] * bp[j];
  }
  #pragma unroll
  for (int off = 1; off < 8; off <<= 1) {
    qw0 += __shfl_xor(qw0, off, 64);
    qw1 += __shfl_xor(qw1, off, 64);
    qw2 += __shfl_xor(qw2, off, 64);
    qb  += __shfl_xor(qb, off, 64);
  }

  const float4 qp = posf4s[qs];
  const int* ip = idx + (size_t)qs * KNB + hf * 8;
  int nb[8];
  #pragma unroll
  for (int k = 0; k < 8; ++k) nb[k] = base + ip[k];   // sorted row

  // ---- pe: this half's 8 neighbor positions in flight at once ----
  float pe[8];
  {
    float4 np[8];
    #pragma unroll
    for (int k = 0; k < 8; ++k) np[k] = posf4s[nb[k]];
    #pragma unroll
    for (int k = 0; k < 8; ++k)
      pe[k] = qw0 * (qp.x - np[k].x) + qw1 * (qp.y - np[k].y) +
              qw2 * (qp.z - np[k].z) + qb;
  }

  // ---- scores: one batch of 8 K-rows, 16 float4 loads in flight ----
  float sc[8];
  {
    float kk[8][8];
    #pragma unroll
    for (int k = 0; k < 8; ++k) {
      const float* kr = Kb + (size_t)nb[k] * D_MODEL + lane * 8;
      *(float4*)&kk[k][0] = *(const float4*)(kr);
      *(float4*)&kk[k][4] = *(const float4*)(kr + 4);
    }
    #pragma unroll
    for (int k = 0; k < 8; ++k) {
      float pdot = 0.f;
      #pragma unroll
      for (int j2 = 0; j2 < 8; ++j2) pdot += q[j2] * kk[k][j2];
      #pragma unroll
      for (int off = 1; off < 8; off <<= 1) pdot += __shfl_xor(pdot, off, 64);
      sc[k] = (pdot + pe[k]) * inv_t;
    }
  }

  // ---- local softmax (this half, per head group) ----
  float m = sc[0];
  #pragma unroll
  for (int k = 1; k < 8; ++k) m = fmaxf(m, sc[k]);
  float ssum = 0.f;
  #pragma unroll
  for (int k = 0; k < 8; ++k) { sc[k] = expf(sc[k] - m); ssum += sc[k]; }

  // ---- local weighted V: one batch of 8 rows ----
  float acc[8];
  #pragma unroll
  for (int j = 0; j < 8; ++j) acc[j] = 0.f;
  {
    float vv[8][8];
    #pragma unroll
    for (int k = 0; k < 8; ++k) {
      const float* vr = Vb + (size_t)nb[k] * D_MODEL + lane * 8;
      *(float4*)&vv[k][0] = *(const float4*)(vr);
      *(float4*)&vv[k][4] = *(const float4*)(vr + 4);
    }
    #pragma unroll
    for (int k = 0; k < 8; ++k) {
      const float wk = sc[k];
      #pragma unroll
      for (int j = 0; j < 8; ++j) acc[j] += wk * vv[k][j];
    }
  }

  // ---- 2-way online-softmax merge via LDS (PER HEAD GROUP) ----
  if ((lane & 7) == 0) { mS[wid][grp] = m; sS[wid][grp] = ssum; }
  if (hf == 1) {
    #pragma unroll
    for (int j = 0; j < 8; ++j) accHalf[qi][j * 64 + lane] = acc[j];
  }
  __syncthreads();
  if (hf == 0) {
    const float mB = mS[wid + 1][grp];
    const float sB = sS[wid + 1][grp];
    const float M = fmaxf(m, mB);
    const float wA = expf(m - M);
    const float wB = expf(mB - M);
    const float inv_s = 1.f / (ssum * wA + sB * wB);

    float a[8];
    #pragma unroll
    for (int j = 0; j < 8; ++j)
      a[j] = (acc[j] * wA + accHalf[qi][j * 64 + lane] * wB) * inv_s;

    ushort4 hi0, hi1;
    unsigned short* oh = Aout + (size_t)qs * 512 + lane * 8;
    hi0.x = f2bf(a[0]);
    hi0.y = f2bf(a[1]);
    hi0.z = f2bf(a[2]);
    hi0.w = f2bf(a[3]);
    hi1.x = f2bf(a[4]);
    hi1.y = f2bf(a[5]);
    hi1.z = f2bf(a[6]);
    hi1.w = f2bf(a[7]);
    *(ushort4*)(oh) = hi0;
    *(ushort4*)(oh + 4) = hi1;
  }
}

// ---------------------------------------------------------------------------
// Kernel 5: LN over sorted proj rows, un-permuting on the final write.
// ---------------------------------------------------------------------------
__global__ __launch_bounds__(256) void ln_kernel(const float* __restrict__ proj,
                                                 const float* __restrict__ feat,
                                                 const int* __restrict__ perm,
                                                 const float* __restrict__ bo,
                                                 const float* __restrict__ gamma,
                                                 const float* __restrict__ beta,
                                                 float* __restrict__ out) {
  const int row = blockIdx.x * 4 + (threadIdx.x >> 6);
  const int lane = threadIdx.x & 63;
  const int orig = (row & ~4095) + perm[row];
  const float* pr = proj + (size_t)row * D_MODEL;
  const float* fr = feat + (size_t)orig * D_MODEL;

  float x[8];
  #pragma unroll
  for (int u = 0; u < 2; ++u) {
    const int c = u * 256 + lane * 4;
    const float4 p = *(const float4*)(pr + c);
    const float4 f = *(const float4*)(fr + c);
    const float4 bb = *(const float4*)(bo + c);
    x[u * 4 + 0] = p.x + bb.x + f.x;
    x[u * 4 + 1] = p.y + bb.y + f.y;
    x[u * 4 + 2] = p.z + bb.z + f.z;
    x[u * 4 + 3] = p.w + bb.w + f.w;
  }
  float sum = 0.f, sumsq = 0.f;
  #pragma unroll
  for (int i = 0; i < 8; ++i) { sum += x[i]; sumsq += x[i] * x[i]; }
  sum = wave_reduce_sum(sum);
  sumsq = wave_reduce_sum(sumsq);
  const float mu = sum * (1.f / D_MODEL);
  const float var = sumsq * (1.f / D_MODEL) - mu * mu;
  const float rstd = rsqrtf(var + LN_EPS);

  #pragma unroll
  for (int u = 0; u < 2; ++u) {
    const int c = u * 256 + lane * 4;
    const float4 g = *(const float4*)(gamma + c);
    const float4 bt = *(const float4*)(beta + c);
    float4 o;
    o.x = (x[u * 4 + 0] - mu) * rstd * g.x + bt.x;
    o.y = (x[u * 4 + 1] - mu) * rstd * g.y + bt.y;
    o.z = (x[u * 4 + 2] - mu) * rstd * g.z + bt.z;
    o.w = (x[u * 4 + 3] - mu) * rstd * g.w + bt.w;
    *(float4*)(out + (size_t)orig * D_MODEL + c) = o;
  }
}

// ---------------------------------------------------------------------------
extern "C" void kernel_launch(void* const* d_in, const int* in_sizes, int n_in,
                              void* d_out, int out_size, void* d_ws, size_t ws_size,
                              hipStream_t stream) {
  const float* positions = (const float*)d_in[0];
  const float* features  = (const float*)d_in[1];
  const float* Wq   = (const float*)d_in[3];
  const float* Wk   = (const float*)d_in[4];
  const float* Wv   = (const float*)d_in[5];
  const float* Wo   = (const float*)d_in[6];
  const float* bo   = (const float*)d_in[7];
  const float* Wpos = (const float*)d_in[8];
  const float* bpos = (const float*)d_in[9];
  const float* temp = (const float*)d_in[10];
  const float* gamma = (const float*)d_in[11];
  const float* beta  = (const float*)d_in[12];

  const int B = 2, N = 4096;
  const int BN = B * N;

  char* w = (char*)d_ws;
  float4* posf4  = (float4*)w;             w += (size_t)BN * sizeof(float4);
  float4* posf4s = (float4*)w;             w += (size_t)BN * sizeof(float4);
  int*    idxb   = (int*)w;                w += (size_t)BN * KNB * sizeof(int);
  int*    permb  = (int*)w;                w += (size_t)BN * sizeof(int);
  int*    histb  = (int*)w;                w += (size_t)B * NBUCK * sizeof(int);
  int*    offb   = (int*)w;                w += (size_t)B * NBUCK * sizeof(int);
  int*    buckb  = (int*)w;                w += (size_t)BN * sizeof(int);
  unsigned short* Abuf = (unsigned short*)w; w += (size_t)BN * 512 * 2;
  unsigned short* BhQKV = (unsigned short*)w; w += (size_t)1536 * 512 * 2;
  unsigned short* BhO = (unsigned short*)w;   w += (size_t)512 * 512 * 2;
  float* Qb   = (float*)w;                 w += (size_t)BN * D_MODEL * sizeof(float);
  float* Kbuf = (float*)w;                 w += (size_t)BN * D_MODEL * sizeof(float);
  float* Vbuf = (float*)d_out;             // dead before LN overwrites d_out
  float* projb = Kbuf;                     // K dead after attention

  zero_hist_kernel<<<(B * NBUCK + 255) / 256, 256, 0, stream>>>(histb, B * NBUCK);
  bucket_kernel<<<(BN + 255) / 256, 256, 0, stream>>>(positions, posf4, histb,
                                                      buckb, BN);
  scan_kernel<<<B, 1024, 0, stream>>>(histb, offb);
  scatter_kernel<<<(BN + 255) / 256, 256, 0, stream>>>(posf4, buckb, offb,
                                                       permb, posf4s, BN);
  knn_kernel<<<BN / 16, 512, 0, stream>>>(posf4s, idxb, N);

  conv_kernel<<<8192, 256, 0, stream>>>(features, permb, Abuf,
                                        Wq, Wk, Wv, Wo, BhQKV, BhO);

  gemm_bf16_kernel<<<768, 256, 0, stream>>>(
      Abuf, BhQKV, Qb, Kbuf, Vbuf, 12);

  attn_kernel<<<BN / 2, 256, 0, stream>>>(Qb, Kbuf, Vbuf, idxb,
                                          posf4s, Wpos, bpos, temp, Abuf,
                                          BN / 2);

  gemm_bf16_kernel<<<256, 256, 0, stream>>>(
      Abuf, BhO, projb, projb, projb, 4);

  ln_kernel<<<BN / 4, 256, 0, stream>>>(projb, features, permb, bo, gamma, beta,
                                        (float*)d_out);
}

// Round 13
// 205.571 us; speedup vs baseline: 1.2128x; 1.0309x over previous
//
#include <hip/hip_runtime.h>
#include <cstdint>

#define D_MODEL 512
#define NUM_HEADS 8
#define D_HEAD 64
#define KNB 16
#define NBUCK 2048
#define LN_EPS 1e-5f
#define FINF 3.4e38f

typedef __bf16 bf16x8v __attribute__((ext_vector_type(8)));
typedef float f32x4v __attribute__((ext_vector_type(4)));
typedef int i32x4 __attribute__((ext_vector_type(4)));
typedef const __attribute__((address_space(1))) unsigned int* gptr_t;
typedef __attribute__((address_space(3))) unsigned int* lptr_t;

__device__ __forceinline__ float wave_reduce_sum(float v) {
  #pragma unroll
  for (int off = 32; off > 0; off >>= 1) v += __shfl_xor(v, off, 64);
  return v;
}

// bf16 helpers (bit-level, round-to-nearest-even)
__device__ __forceinline__ unsigned short f2bf(float x) {
  unsigned int u = __float_as_uint(x);
  u = (u + 0x7fffu + ((u >> 16) & 1u)) >> 16;
  return (unsigned short)u;
}
__device__ __forceinline__ float bf2f(unsigned short h) {
  return __uint_as_float(((unsigned int)h) << 16);
}
// unpack 8 bf16 (one 16B vector) to 8 floats: 2 bit-ops per pair.
__device__ __forceinline__ void unpack8(i32x4 v, float* o) {
  #pragma unroll
  for (int i = 0; i < 4; ++i) {
    const unsigned u = (unsigned)v[i];
    o[2 * i]     = __uint_as_float(u << 16);
    o[2 * i + 1] = __uint_as_float(u & 0xffff0000u);
  }
}

// Morton helpers: bucketing quality only affects SPEED.
__device__ __forceinline__ unsigned spread3(unsigned x) {
  x &= 0x3FFu;
  x = (x | (x << 16)) & 0x030000FFu;
  x = (x | (x << 8))  & 0x0300F00Fu;
  x = (x | (x << 4))  & 0x030C30C3u;
  x = (x | (x << 2))  & 0x09249249u;
  return x;
}
__device__ __forceinline__ unsigned quant10(float v) {
  int q = (int)((v + 6.f) * (1023.f / 12.f));
  q = q < 0 ? 0 : (q > 1023 ? 1023 : q);
  return (unsigned)q;
}

// 64-lane bitonic sort ascending by (d, j) lexicographic (pairs distinct).
__device__ __forceinline__ void bitonic64(float& d, int& j, int lane) {
  #pragma unroll
  for (int k = 2; k <= 64; k <<= 1) {
    #pragma unroll
    for (int s = k >> 1; s > 0; s >>= 1) {
      const float od = __shfl_xor(d, s, 64);
      const int   oj = __shfl_xor(j, s, 64);
      const bool up = ((lane & k) == 0);
      const bool lower = ((lane & s) == 0);
      const bool oless = (od < d) || (od == d && oj < j);
      if ((lower == up) ? oless : !oless) { d = od; j = oj; }
    }
  }
}

// ---------------------------------------------------------------------------
// Kernel 0a: zero bucket histogram
// ---------------------------------------------------------------------------
__global__ void zero_hist_kernel(int* __restrict__ hist, int n) {
  const int t = blockIdx.x * blockDim.x + threadIdx.x;
  if (t < n) hist[t] = 0;
}

// ---------------------------------------------------------------------------
// Kernel 0b: pad pos -> float4, Morton bucket (top 11 bits), histogram.
// ---------------------------------------------------------------------------
__global__ void bucket_kernel(const float* __restrict__ pos,
                              float4* __restrict__ posf4,
                              int* __restrict__ hist,
                              int* __restrict__ bucketid, int total) {
  const int t = blockIdx.x * blockDim.x + threadIdx.x;
  if (t >= total) return;
  const float4 p = make_float4(pos[t * 3], pos[t * 3 + 1], pos[t * 3 + 2], 0.f);
  posf4[t] = p;
  const unsigned code = (spread3(quant10(p.z)) << 2) |
                        (spread3(quant10(p.y)) << 1) | spread3(quant10(p.x));
  const int bk = code >> 19;
  const int b = t >> 12;
  bucketid[t] = bk;
  atomicAdd(&hist[b * NBUCK + bk], 1);
}

// ---------------------------------------------------------------------------
// Kernel 0c: exclusive scan of 2048 buckets per batch (one block per batch).
// ---------------------------------------------------------------------------
__global__ __launch_bounds__(1024) void scan_kernel(const int* __restrict__ hist,
                                                    int* __restrict__ off) {
  __shared__ int lsum[16];
  const int b = blockIdx.x;
  const int tid = threadIdx.x;
  const int lane = tid & 63, wv = tid >> 6;
  const int h0 = hist[b * NBUCK + 2 * tid];
  const int h1 = hist[b * NBUCK + 2 * tid + 1];
  int v = h0 + h1;
  #pragma unroll
  for (int d = 1; d < 64; d <<= 1) {
    const int u = __shfl_up(v, d, 64);
    if (lane >= d) v += u;
  }
  if (lane == 63) lsum[wv] = v;
  __syncthreads();
  if (wv == 0) {
    int s = (lane < 16) ? lsum[lane] : 0;
    #pragma unroll
    for (int d = 1; d < 16; d <<= 1) {
      const int u = __shfl_up(s, d, 64);
      if (lane >= d) s += u;
    }
    if (lane < 16) lsum[lane] = s;
  }
  __syncthreads();
  const int base = (wv > 0) ? lsum[wv - 1] : 0;
  const int excl = v + base - (h0 + h1);
  off[b * NBUCK + 2 * tid] = excl;
  off[b * NBUCK + 2 * tid + 1] = excl + h0;
}

// ---------------------------------------------------------------------------
// Kernel 0d: scatter into bucket order.
// ---------------------------------------------------------------------------
__global__ void scatter_kernel(const float4* __restrict__ posf4,
                               const int* __restrict__ bucketid,
                               int* __restrict__ off,
                               int* __restrict__ perm,
                               float4* __restrict__ posf4s, int total) {
  const int t = blockIdx.x * blockDim.x + threadIdx.x;
  if (t >= total) return;
  const int b = t >> 12;
  const int i = t & 4095;
  const int slot = atomicAdd(&off[b * NBUCK + bucketid[t]], 1);
  perm[b * 4096 + slot] = i;
  posf4s[b * 4096 + slot] = posf4[t];
}

// ---------------------------------------------------------------------------
// Kernel 1: kNN (proven round-4 version: 512 threads, float4 LDS, 72KB).
// ---------------------------------------------------------------------------
__global__ __launch_bounds__(512, 4) void knn_kernel(const float4* __restrict__ posf4s,
                                                     int* __restrict__ idx_out,
                                                     int N) {
  __shared__ float4 pts[4096];      // 64 KB: whole batch, staged once
  __shared__ float scrD[16 * 64];   // 4 KB: survivor distances (per query)
  __shared__ int   scrJ[16 * 64];   // 4 KB: survivor sorted-ids

  const int tid = threadIdx.x;
  const int lane = tid & 63;
  const int wid = tid >> 6;                 // 0..7
  const int qs0 = blockIdx.x * 16 + wid * 2;  // this wave's first query (sorted id)
  const int base = qs0 & ~4095;
  const int n0 = qs0 & 4095;                // batch-local sorted positions
  const int n1 = n0 + 1;
  const float4* pb = posf4s + base;

  // ---- stage the whole 4096-point batch into LDS (8 x 16B per thread) ----
  #pragma unroll
  for (int i = 0; i < 8; ++i) {
    const int c = wid * 8 + i;              // chunk 0..63, 64 points each
    __builtin_amdgcn_global_load_lds((gptr_t)(pb + c * 64 + lane),
                                     (lptr_t)&pts[c * 64], 16, 0, 0);
  }
  __syncthreads();

  const float4 qp0 = pts[n0];
  const float4 qp1 = pts[n1];

  // ---- scan (shared reads): per-lane minima for both queries ----
  float lmin0 = FINF, lmin1 = FINF;
  #pragma unroll 8
  for (int it = 0; it < 64; ++it) {
    const int j = (it << 6) + lane;
    const float4 p = pts[j];
    float dx = qp0.x - p.x, dy = qp0.y - p.y, dz = qp0.z - p.z;
    float d0 = dx * dx + dy * dy + dz * dz;
    dx = qp1.x - p.x; dy = qp1.y - p.y; dz = qp1.z - p.z;
    float d1 = dx * dx + dy * dy + dz * dz;
    if (j == n0) d0 = FINF;
    if (j == n1) d1 = FINF;
    lmin0 = fminf(lmin0, d0);
    lmin1 = fminf(lmin1, d1);
  }

  // ---- tau = 16th smallest lane-min (guarantees >=16 survivors).
  // Value-only bitonic, two queries interleaved for ILP. ----
  float a0 = lmin0, a1 = lmin1;
  #pragma unroll
  for (int k = 2; k <= 64; k <<= 1) {
    #pragma unroll
    for (int s = k >> 1; s > 0; s >>= 1) {
      const bool keepmin = (((lane & k) == 0) == ((lane & s) == 0));
      const float b0 = __shfl_xor(a0, s, 64);
      const float b1 = __shfl_xor(a1, s, 64);
      a0 = keepmin ? fminf(a0, b0) : fmaxf(a0, b0);
      a1 = keepmin ? fminf(a1, b1) : fmaxf(a1, b1);
    }
  }
  float tau0 = __shfl(a0, 15, 64);
  float tau1 = __shfl(a1, 15, 64);

  // ---- compaction (shared reads, recompute d): survivors -> LDS, cap 64 ----
  const unsigned long long lt = (1ull << lane) - 1ull;
  const int wq0 = wid * 2, wq1 = wid * 2 + 1;
  int cnt0 = 0, cnt1 = 0;
  #pragma unroll 4
  for (int it = 0; it < 64; ++it) {
    const int j = (it << 6) + lane;
    const float4 p = pts[j];
    float dx = qp0.x - p.x, dy = qp0.y - p.y, dz = qp0.z - p.z;
    float d0 = dx * dx + dy * dy + dz * dz;
    dx = qp1.x - p.x; dy = qp1.y - p.y; dz = qp1.z - p.z;
    float d1 = dx * dx + dy * dy + dz * dz;
    if (j == n0) d0 = FINF;
    if (j == n1) d1 = FINF;
    const bool p0 = (d0 <= tau0);
    const bool p1 = (d1 <= tau1);
    const unsigned long long m0 = __ballot(p0);
    const unsigned long long m1 = __ballot(p1);
    if (p0) {
      const int s0 = cnt0 + __popcll(m0 & lt);
      if (s0 < 64) { scrD[wq0 * 64 + s0] = d0; scrJ[wq0 * 64 + s0] = j; }
    }
    if (p1) {
      const int s1 = cnt1 + __popcll(m1 & lt);
      if (s1 < 64) { scrD[wq1 * 64 + s1] = d1; scrJ[wq1 * 64 + s1] = j; }
    }
    cnt0 += (int)__popcll(m0);
    cnt1 += (int)__popcll(m1);
  }

  // ---- per-query: sort survivors; rare retry tightens tau until cnt<=64 ----
  for (int q = 0; q < 2; ++q) {
    const int wq = wid * 2 + q;
    int cnt = q ? cnt1 : cnt0;
    float tau = q ? tau1 : tau0;
    const float4 qp = q ? qp1 : qp0;
    const int n = q ? n1 : n0;
    const int qs = qs0 + q;

    int m = cnt < 64 ? cnt : 64;
    float d = (lane < m) ? scrD[wq * 64 + lane] : FINF;
    int  jj = (lane < m) ? scrJ[wq * 64 + lane] : 0x40000000 + lane;
    bitonic64(d, jj, lane);

    while (cnt > 64) {
      // 16th smallest of 64 captured global elements -> valid tighter tau
      const float ntau = __shfl(d, 15, 64);
      if (!(ntau < tau)) break;   // degenerate exact-tie plateau: accept
      tau = ntau;
      cnt = 0;
      #pragma unroll 4
      for (int it = 0; it < 64; ++it) {
        const int j = (it << 6) + lane;
        const float4 p = pts[j];
        const float ddx = qp.x - p.x, ddy = qp.y - p.y, ddz = qp.z - p.z;
        float dd = ddx * ddx + ddy * ddy + ddz * ddz;
        if (j == n) dd = FINF;
        const bool pr = (dd <= tau);
        const unsigned long long mm = __ballot(pr);
        if (pr) {
          const int sl = cnt + __popcll(mm & lt);
          if (sl < 64) { scrD[wq * 64 + sl] = dd; scrJ[wq * 64 + sl] = j; }
        }
        cnt += (int)__popcll(mm);
      }
      m = cnt < 64 ? cnt : 64;
      d = (lane < m) ? scrD[wq * 64 + lane] : FINF;
      jj = (lane < m) ? scrJ[wq * 64 + lane] : 0x40000000 + lane;
      bitonic64(d, jj, lane);
    }

    if (lane < KNB) idx_out[(size_t)qs * KNB + lane] = jj;
  }
}

// ---------------------------------------------------------------------------
// Kernel 2: MERGED conv (feat + weights) — bf16-only (r12 verified).
// ---------------------------------------------------------------------------
__global__ __launch_bounds__(256) void conv_kernel(const float* __restrict__ src,
                                                   const int* __restrict__ perm,
                                                   unsigned short* __restrict__ dst,
                                                   const float* __restrict__ Wq,
                                                   const float* __restrict__ Wk,
                                                   const float* __restrict__ Wv,
                                                   const float* __restrict__ Wo,
                                                   unsigned short* __restrict__ BhQKV,
                                                   unsigned short* __restrict__ BhO) {
  const int b = blockIdx.x;
  if (b < 4096) {
    const int t = b * 256 + threadIdx.x;
    const int f = t * 4;
    const int row = f >> 9;
    const int col = f & 511;
    const int orig = (row & ~4095) + perm[row];
    const float4 v = *(const float4*)(src + (size_t)orig * 512 + col);
    ushort4 h;
    h.x = f2bf(v.x);
    h.y = f2bf(v.y);
    h.z = f2bf(v.z);
    h.w = f2bf(v.w);
    *(ushort4*)(dst + (size_t)row * 512 + col) = h;
  } else {
    const int bb = b - 4096;
    const int wsel = bb >> 10;
    const int i = ((bb & 1023) << 8) + threadIdx.x;
    const int n = i >> 9;
    const int k = i & 511;
    const float* wsrc = wsel == 0 ? Wq : wsel == 1 ? Wk : wsel == 2 ? Wv : Wo;
    unsigned short* dh = wsel < 3 ? BhQKV + (size_t)(wsel * 512 + n) * 512
                                  : BhO + (size_t)n * 512;
    dh[k] = f2bf(wsrc[(size_t)k * 512 + n]);
  }
}

// ---------------------------------------------------------------------------
// Kernel 3: bf16 MFMA GEMM (r12 verified schedule) — Round 13: templated
// output dtype. OUT_BF16=1 for QKV (halves WRITE, K+V fit L2 for attn
// gathers); OUT_BF16=0 for proj (feeds LN in fp32, no extra quant).
// ---------------------------------------------------------------------------
template <int OUT_BF16>
__global__ __launch_bounds__(256, 2) void gemm_bf16_kernel(
    const unsigned short* __restrict__ A,    // M x 512 bf16
    const unsigned short* __restrict__ B,    // Ncols x 512 bf16
    void* __restrict__ C0v, void* __restrict__ C1v, void* __restrict__ C2v,
    int nbn) {
  __shared__ unsigned short As[8192];   // 16 KB
  __shared__ unsigned short Bs[8192];   // 16 KB

  const int tid = threadIdx.x;
  const int wid = tid >> 6;
  const int lane = tid & 63;
  const int lm = lane & 15;
  const int kq = lane >> 4;
  const int wr = wid >> 1;
  const int wc = wid & 1;
  const int bid = blockIdx.x;
  const int xcd = bid & 7;
  const int i = bid >> 3;
  const int bm = xcd * 8 + i / nbn;
  const int bn = i % nbn;
  const int rowA0 = bm * 128;
  const int rowB0 = bn * 128;

  f32x4v acc[4][4];
  #pragma unroll
  for (int mi = 0; mi < 4; ++mi)
    #pragma unroll
    for (int ni = 0; ni < 4; ++ni) {
      f32x4v z = {0.f, 0.f, 0.f, 0.f};
      acc[mi][ni] = z;
    }

  auto stage64 = [&](unsigned short* dst, const unsigned short* gsrc,
                     int grow0, int gk0) {
    #pragma unroll
    for (int i2 = 0; i2 < 4; ++i2) {
      const int c = wid * 256 + i2 * 64 + lane;   // chunk 0..1023
      const int row = c >> 3;
      const int gq = (c & 7) ^ (row & 7);
      const unsigned short* ga =
          gsrc + (size_t)(grow0 + row) * 512 + gk0 + gq * 8;
      __builtin_amdgcn_global_load_lds((gptr_t)ga,
          (lptr_t)(dst + (size_t)(wid * 256 + i2 * 64) * 8), 16, 0, 0);
    }
  };
  auto rd64 = [&](const unsigned short* src, int row, int g) -> i32x4 {
    const int sl = row * 8 + (g ^ (row & 7));
    return *(const i32x4*)(src + (size_t)sl * 8);
  };

  // ---- prologue: stage tile k0=0 ----
  stage64(As, A, rowA0, 0);
  stage64(Bs, B, rowB0, 0);

  for (int k0 = 0; k0 < 512; k0 += 64) {
    __syncthreads();   // (a) stage landed (drains vmcnt), LDS consistent
    i32x4 ah[2][4], bb[2][4];
    #pragma unroll
    for (int kh = 0; kh < 2; ++kh) {
      const int g = kh * 4 + kq;
      #pragma unroll
      for (int mi = 0; mi < 4; ++mi)
        ah[kh][mi] = rd64(As, wr * 64 + mi * 16 + lm, g);
      #pragma unroll
      for (int ni = 0; ni < 4; ++ni)
        bb[kh][ni] = rd64(Bs, wc * 64 + ni * 16 + lm, g);
    }
    __syncthreads();   // (b) all waves done reading LDS

    if (k0 < 448) {
      stage64(As, A, rowA0, k0 + 64);
      stage64(Bs, B, rowB0, k0 + 64);
    }

    #pragma unroll
    for (int kh = 0; kh < 2; ++kh)
      #pragma unroll
      for (int mi = 0; mi < 4; ++mi)
        #pragma unroll
        for (int ni = 0; ni < 4; ++ni)
          acc[mi][ni] = __builtin_amdgcn_mfma_f32_16x16x32_bf16(
              __builtin_bit_cast(bf16x8v, ah[kh][mi]),
              __builtin_bit_cast(bf16x8v, bb[kh][ni]), acc[mi][ni], 0, 0, 0);
  }

  const int sel = bn >> 2;
  const int r0 = bm * 128 + wr * 64;
  const int c0 = ((bn & 3) << 7) + wc * 64;
  // C/D layout: col = lane&15, row = (lane>>4)*4 + reg   [m89/m91]
  if constexpr (OUT_BF16) {
    unsigned short* Cb = (unsigned short*)(sel == 0 ? C0v : sel == 1 ? C1v : C2v);
    #pragma unroll
    for (int mi = 0; mi < 4; ++mi)
      #pragma unroll
      for (int ni = 0; ni < 4; ++ni) {
        unsigned short* Cp =
            Cb + (size_t)(r0 + mi * 16 + kq * 4) * 512 + c0 + ni * 16 + lm;
        #pragma unroll
        for (int r = 0; r < 4; ++r) Cp[(size_t)r * 512] = f2bf(acc[mi][ni][r]);
      }
  } else {
    float* Cb = (float*)(sel == 0 ? C0v : sel == 1 ? C1v : C2v);
    #pragma unroll
    for (int mi = 0; mi < 4; ++mi)
      #pragma unroll
      for (int ni = 0; ni < 4; ++ni) {
        float* Cp = Cb + (size_t)(r0 + mi * 16 + kq * 4) * 512 + c0 + ni * 16 + lm;
        #pragma unroll
        for (int r = 0; r < 4; ++r) Cp[(size_t)r * 512] = acc[mi][ni][r];
      }
  }
}

// ---------------------------------------------------------------------------
// Kernel 4: local attention — 2 waves/query, per-head merge (r11 verified).
// Round 13: Q/K/V are bf16 (one 16B load per row per lane; K+V L2-resident).
// ---------------------------------------------------------------------------
__global__ __launch_bounds__(256) void attn_kernel(const unsigned short* __restrict__ Q,
                                                   const unsigned short* __restrict__ Kb,
                                                   const unsigned short* __restrict__ Vb,
                                                   const int* __restrict__ idx,
                                                   const float4* __restrict__ posf4s,
                                                   const float* __restrict__ Wpos,
                                                   const float* __restrict__ bpos,
                                                   const float* __restrict__ temperature,
                                                   unsigned short* __restrict__ Aout,
                                                   int nblocks) {
  __shared__ float mS[4][8], sS[4][8];
  __shared__ float accHalf[2][512];   // half-B partial V-acc per query

  int bid = blockIdx.x;
  bid = (bid & 7) * (nblocks >> 3) + (bid >> 3);        // XCD-contiguous
  const int wid = threadIdx.x >> 6;
  const int lane = threadIdx.x & 63;
  const int qi = wid >> 1;            // query within block (0..1)
  const int hf = wid & 1;             // neighbor half (0..1)
  const int qs = bid * 2 + qi;
  const int s = lane & 7;
  const int grp = lane >> 3;          // head group (0..7)
  const int base = qs & ~4095;

  const float inv_t = 1.0f / temperature[0];

  float q[8];
  unpack8(*(const i32x4*)(Q + (size_t)qs * D_MODEL + lane * 8), q);

  float wp[3][8], bp[8];
  #pragma unroll
  for (int c = 0; c < 3; ++c) {
    *(float4*)&wp[c][0] = *(const float4*)(Wpos + c * 128 + s * 8);
    *(float4*)&wp[c][4] = *(const float4*)(Wpos + c * 128 + s * 8 + 4);
  }
  *(float4*)&bp[0] = *(const float4*)(bpos + s * 8);
  *(float4*)&bp[4] = *(const float4*)(bpos + s * 8 + 4);
  float qw0 = 0.f, qw1 = 0.f, qw2 = 0.f, qb = 0.f;
  #pragma unroll
  for (int j = 0; j < 8; ++j) {
    qw0 += q[j] * wp[0][j];
    qw1 += q[j] * wp[1][j];
    qw2 += q[j] * wp[2][j];
    qb  += q[j] * bp[j];
  }
  #pragma unroll
  for (int off = 1; off < 8; off <<= 1) {
    qw0 += __shfl_xor(qw0, off, 64);
    qw1 += __shfl_xor(qw1, off, 64);
    qw2 += __shfl_xor(qw2, off, 64);
    qb  += __shfl_xor(qb, off, 64);
  }

  const float4 qp = posf4s[qs];
  const int* ip = idx + (size_t)qs * KNB + hf * 8;
  int nb[8];
  #pragma unroll
  for (int k = 0; k < 8; ++k) nb[k] = base + ip[k];   // sorted row

  // ---- pe: this half's 8 neighbor positions in flight at once ----
  float pe[8];
  {
    float4 np[8];
    #pragma unroll
    for (int k = 0; k < 8; ++k) np[k] = posf4s[nb[k]];
    #pragma unroll
    for (int k = 0; k < 8; ++k)
      pe[k] = qw0 * (qp.x - np[k].x) + qw1 * (qp.y - np[k].y) +
              qw2 * (qp.z - np[k].z) + qb;
  }

  // ---- scores: 8 K-rows, one 16B load each, all in flight ----
  float sc[8];
  {
    i32x4 kv[8];
    #pragma unroll
    for (int k = 0; k < 8; ++k)
      kv[k] = *(const i32x4*)(Kb + (size_t)nb[k] * D_MODEL + lane * 8);
    #pragma unroll
    for (int k = 0; k < 8; ++k) {
      float kk[8];
      unpack8(kv[k], kk);
      float pdot = 0.f;
      #pragma unroll
      for (int j2 = 0; j2 < 8; ++j2) pdot += q[j2] * kk[j2];
      #pragma unroll
      for (int off = 1; off < 8; off <<= 1) pdot += __shfl_xor(pdot, off, 64);
      sc[k] = (pdot + pe[k]) * inv_t;
    }
  }

  // ---- local softmax (this half, per head group) ----
  float m = sc[0];
  #pragma unroll
  for (int k = 1; k < 8; ++k) m = fmaxf(m, sc[k]);
  float ssum = 0.f;
  #pragma unroll
  for (int k = 0; k < 8; ++k) { sc[k] = expf(sc[k] - m); ssum += sc[k]; }

  // ---- local weighted V: 8 rows, one 16B load each ----
  float acc[8];
  #pragma unroll
  for (int j = 0; j < 8; ++j) acc[j] = 0.f;
  {
    i32x4 vv[8];
    #pragma unroll
    for (int k = 0; k < 8; ++k)
      vv[k] = *(const i32x4*)(Vb + (size_t)nb[k] * D_MODEL + lane * 8);
    #pragma unroll
    for (int k = 0; k < 8; ++k) {
      float vf[8];
      unpack8(vv[k], vf);
      const float wk = sc[k];
      #pragma unroll
      for (int j = 0; j < 8; ++j) acc[j] += wk * vf[j];
    }
  }

  // ---- 2-way online-softmax merge via LDS (PER HEAD GROUP) ----
  if ((lane & 7) == 0) { mS[wid][grp] = m; sS[wid][grp] = ssum; }
  if (hf == 1) {
    #pragma unroll
    for (int j = 0; j < 8; ++j) accHalf[qi][j * 64 + lane] = acc[j];
  }
  __syncthreads();
  if (hf == 0) {
    const float mB = mS[wid + 1][grp];
    const float sB = sS[wid + 1][grp];
    const float M = fmaxf(m, mB);
    const float wA = expf(m - M);
    const float wB = expf(mB - M);
    const float inv_s = 1.f / (ssum * wA + sB * wB);

    float a[8];
    #pragma unroll
    for (int j = 0; j < 8; ++j)
      a[j] = (acc[j] * wA + accHalf[qi][j * 64 + lane] * wB) * inv_s;

    ushort4 hi0, hi1;
    unsigned short* oh = Aout + (size_t)qs * 512 + lane * 8;
    hi0.x = f2bf(a[0]);
    hi0.y = f2bf(a[1]);
    hi0.z = f2bf(a[2]);
    hi0.w = f2bf(a[3]);
    hi1.x = f2bf(a[4]);
    hi1.y = f2bf(a[5]);
    hi1.z = f2bf(a[6]);
    hi1.w = f2bf(a[7]);
    *(ushort4*)(oh) = hi0;
    *(ushort4*)(oh + 4) = hi1;
  }
}

// ---------------------------------------------------------------------------
// Kernel 5: LN over sorted proj rows, un-permuting on the final write.
// ---------------------------------------------------------------------------
__global__ __launch_bounds__(256) void ln_kernel(const float* __restrict__ proj,
                                                 const float* __restrict__ feat,
                                                 const int* __restrict__ perm,
                                                 const float* __restrict__ bo,
                                                 const float* __restrict__ gamma,
                                                 const float* __restrict__ beta,
                                                 float* __restrict__ out) {
  const int row = blockIdx.x * 4 + (threadIdx.x >> 6);
  const int lane = threadIdx.x & 63;
  const int orig = (row & ~4095) + perm[row];
  const float* pr = proj + (size_t)row * D_MODEL;
  const float* fr = feat + (size_t)orig * D_MODEL;

  float x[8];
  #pragma unroll
  for (int u = 0; u < 2; ++u) {
    const int c = u * 256 + lane * 4;
    const float4 p = *(const float4*)(pr + c);
    const float4 f = *(const float4*)(fr + c);
    const float4 bb = *(const float4*)(bo + c);
    x[u * 4 + 0] = p.x + bb.x + f.x;
    x[u * 4 + 1] = p.y + bb.y + f.y;
    x[u * 4 + 2] = p.z + bb.z + f.z;
    x[u * 4 + 3] = p.w + bb.w + f.w;
  }
  float sum = 0.f, sumsq = 0.f;
  #pragma unroll
  for (int i = 0; i < 8; ++i) { sum += x[i]; sumsq += x[i] * x[i]; }
  sum = wave_reduce_sum(sum);
  sumsq = wave_reduce_sum(sumsq);
  const float mu = sum * (1.f / D_MODEL);
  const float var = sumsq * (1.f / D_MODEL) - mu * mu;
  const float rstd = rsqrtf(var + LN_EPS);

  #pragma unroll
  for (int u = 0; u < 2; ++u) {
    const int c = u * 256 + lane * 4;
    const float4 g = *(const float4*)(gamma + c);
    const float4 bt = *(const float4*)(beta + c);
    float4 o;
    o.x = (x[u * 4 + 0] - mu) * rstd * g.x + bt.x;
    o.y = (x[u * 4 + 1] - mu) * rstd * g.y + bt.y;
    o.z = (x[u * 4 + 2] - mu) * rstd * g.z + bt.z;
    o.w = (x[u * 4 + 3] - mu) * rstd * g.w + bt.w;
    *(float4*)(out + (size_t)orig * D_MODEL + c) = o;
  }
}

// ---------------------------------------------------------------------------
extern "C" void kernel_launch(void* const* d_in, const int* in_sizes, int n_in,
                              void* d_out, int out_size, void* d_ws, size_t ws_size,
                              hipStream_t stream) {
  const float* positions = (const float*)d_in[0];
  const float* features  = (const float*)d_in[1];
  const float* Wq   = (const float*)d_in[3];
  const float* Wk   = (const float*)d_in[4];
  const float* Wv   = (const float*)d_in[5];
  const float* Wo   = (const float*)d_in[6];
  const float* bo   = (const float*)d_in[7];
  const float* Wpos = (const float*)d_in[8];
  const float* bpos = (const float*)d_in[9];
  const float* temp = (const float*)d_in[10];
  const float* gamma = (const float*)d_in[11];
  const float* beta  = (const float*)d_in[12];

  const int B = 2, N = 4096;
  const int BN = B * N;

  char* w = (char*)d_ws;
  float4* posf4  = (float4*)w;             w += (size_t)BN * sizeof(float4);
  float4* posf4s = (float4*)w;             w += (size_t)BN * sizeof(float4);
  int*    idxb   = (int*)w;                w += (size_t)BN * KNB * sizeof(int);
  int*    permb  = (int*)w;                w += (size_t)BN * sizeof(int);
  int*    histb  = (int*)w;                w += (size_t)B * NBUCK * sizeof(int);
  int*    offb   = (int*)w;                w += (size_t)B * NBUCK * sizeof(int);
  int*    buckb  = (int*)w;                w += (size_t)BN * sizeof(int);
  unsigned short* Abuf = (unsigned short*)w; w += (size_t)BN * 512 * 2;
  unsigned short* BhQKV = (unsigned short*)w; w += (size_t)1536 * 512 * 2;
  unsigned short* BhO = (unsigned short*)w;   w += (size_t)512 * 512 * 2;
  unsigned short* Qb16 = (unsigned short*)w;  w += (size_t)BN * 512 * 2;   // 8 MB
  unsigned short* Kb16 = (unsigned short*)w;  w += (size_t)BN * 512 * 2;   // 8 MB
  unsigned short* Vb16 = (unsigned short*)d_out;   // 8 MB of out; dead before LN
  float* projb = (float*)Qb16;             // 16 MB overlays Qb16+Kb16 (dead)

  zero_hist_kernel<<<(B * NBUCK + 255) / 256, 256, 0, stream>>>(histb, B * NBUCK);
  bucket_kernel<<<(BN + 255) / 256, 256, 0, stream>>>(positions, posf4, histb,
                                                      buckb, BN);
  scan_kernel<<<B, 1024, 0, stream>>>(histb, offb);
  scatter_kernel<<<(BN + 255) / 256, 256, 0, stream>>>(posf4, buckb, offb,
                                                       permb, posf4s, BN);
  knn_kernel<<<BN / 16, 512, 0, stream>>>(posf4s, idxb, N);

  conv_kernel<<<8192, 256, 0, stream>>>(features, permb, Abuf,
                                        Wq, Wk, Wv, Wo, BhQKV, BhO);

  gemm_bf16_kernel<1><<<768, 256, 0, stream>>>(
      Abuf, BhQKV, Qb16, Kb16, Vb16, 12);

  attn_kernel<<<BN / 2, 256, 0, stream>>>(Qb16, Kb16, Vb16, idxb,
                                          posf4s, Wpos, bpos, temp, Abuf,
                                          BN / 2);

  gemm_bf16_kernel<0><<<256, 256, 0, stream>>>(
      Abuf, BhO, projb, projb, projb, 4);

  ln_kernel<<<BN / 4, 256, 0, stream>>>(projb, features, permb, bo, gamma, beta,
                                        (float*)d_out);
}

// Round 14
// 198.032 us; speedup vs baseline: 1.2590x; 1.0381x over previous
//
#include <hip/hip_runtime.h>
#include <cstdint>

#define D_MODEL 512
#define NUM_HEADS 8
#define D_HEAD 64
#define KNB 16
#define NBUCK 2048
#define LN_EPS 1e-5f
#define FINF 3.4e38f

typedef __bf16 bf16x8v __attribute__((ext_vector_type(8)));
typedef float f32x4v __attribute__((ext_vector_type(4)));
typedef int i32x4 __attribute__((ext_vector_type(4)));
typedef const __attribute__((address_space(1))) unsigned int* gptr_t;
typedef __attribute__((address_space(3))) unsigned int* lptr_t;

__device__ __forceinline__ float wave_reduce_sum(float v) {
  #pragma unroll
  for (int off = 32; off > 0; off >>= 1) v += __shfl_xor(v, off, 64);
  return v;
}

// bf16 helpers (bit-level, round-to-nearest-even)
__device__ __forceinline__ unsigned short f2bf(float x) {
  unsigned int u = __float_as_uint(x);
  u = (u + 0x7fffu + ((u >> 16) & 1u)) >> 16;
  return (unsigned short)u;
}
__device__ __forceinline__ float bf2f(unsigned short h) {
  return __uint_as_float(((unsigned int)h) << 16);
}
// unpack 8 bf16 (one 16B vector) to 8 floats: 2 bit-ops per pair.
__device__ __forceinline__ void unpack8(i32x4 v, float* o) {
  #pragma unroll
  for (int i = 0; i < 4; ++i) {
    const unsigned u = (unsigned)v[i];
    o[2 * i]     = __uint_as_float(u << 16);
    o[2 * i + 1] = __uint_as_float(u & 0xffff0000u);
  }
}

// Morton helpers: bucketing quality only affects SPEED.
__device__ __forceinline__ unsigned spread3(unsigned x) {
  x &= 0x3FFu;
  x = (x | (x << 16)) & 0x030000FFu;
  x = (x | (x << 8))  & 0x0300F00Fu;
  x = (x | (x << 4))  & 0x030C30C3u;
  x = (x | (x << 2))  & 0x09249249u;
  return x;
}
__device__ __forceinline__ unsigned quant10(float v) {
  int q = (int)((v + 6.f) * (1023.f / 12.f));
  q = q < 0 ? 0 : (q > 1023 ? 1023 : q);
  return (unsigned)q;
}

// 64-lane bitonic sort ascending by (d, j) lexicographic (pairs distinct).
__device__ __forceinline__ void bitonic64(float& d, int& j, int lane) {
  #pragma unroll
  for (int k = 2; k <= 64; k <<= 1) {
    #pragma unroll
    for (int s = k >> 1; s > 0; s >>= 1) {
      const float od = __shfl_xor(d, s, 64);
      const int   oj = __shfl_xor(j, s, 64);
      const bool up = ((lane & k) == 0);
      const bool lower = ((lane & s) == 0);
      const bool oless = (od < d) || (od == d && oj < j);
      if ((lower == up) ? oless : !oless) { d = od; j = oj; }
    }
  }
}

// ---------------------------------------------------------------------------
// Kernel 0a: zero bucket histogram
// ---------------------------------------------------------------------------
__global__ void zero_hist_kernel(int* __restrict__ hist, int n) {
  const int t = blockIdx.x * blockDim.x + threadIdx.x;
  if (t < n) hist[t] = 0;
}

// ---------------------------------------------------------------------------
// Kernel 0b: pad pos -> float4, Morton bucket (top 11 bits), histogram.
// ---------------------------------------------------------------------------
__global__ void bucket_kernel(const float* __restrict__ pos,
                              float4* __restrict__ posf4,
                              int* __restrict__ hist,
                              int* __restrict__ bucketid, int total) {
  const int t = blockIdx.x * blockDim.x + threadIdx.x;
  if (t >= total) return;
  const float4 p = make_float4(pos[t * 3], pos[t * 3 + 1], pos[t * 3 + 2], 0.f);
  posf4[t] = p;
  const unsigned code = (spread3(quant10(p.z)) << 2) |
                        (spread3(quant10(p.y)) << 1) | spread3(quant10(p.x));
  const int bk = code >> 19;
  const int b = t >> 12;
  bucketid[t] = bk;
  atomicAdd(&hist[b * NBUCK + bk], 1);
}

// ---------------------------------------------------------------------------
// Kernel 0c: exclusive scan of 2048 buckets per batch (one block per batch).
// ---------------------------------------------------------------------------
__global__ __launch_bounds__(1024) void scan_kernel(const int* __restrict__ hist,
                                                    int* __restrict__ off) {
  __shared__ int lsum[16];
  const int b = blockIdx.x;
  const int tid = threadIdx.x;
  const int lane = tid & 63, wv = tid >> 6;
  const int h0 = hist[b * NBUCK + 2 * tid];
  const int h1 = hist[b * NBUCK + 2 * tid + 1];
  int v = h0 + h1;
  #pragma unroll
  for (int d = 1; d < 64; d <<= 1) {
    const int u = __shfl_up(v, d, 64);
    if (lane >= d) v += u;
  }
  if (lane == 63) lsum[wv] = v;
  __syncthreads();
  if (wv == 0) {
    int s = (lane < 16) ? lsum[lane] : 0;
    #pragma unroll
    for (int d = 1; d < 16; d <<= 1) {
      const int u = __shfl_up(s, d, 64);
      if (lane >= d) s += u;
    }
    if (lane < 16) lsum[lane] = s;
  }
  __syncthreads();
  const int base = (wv > 0) ? lsum[wv - 1] : 0;
  const int excl = v + base - (h0 + h1);
  off[b * NBUCK + 2 * tid] = excl;
  off[b * NBUCK + 2 * tid + 1] = excl + h0;
}

// ---------------------------------------------------------------------------
// Kernel 0d: scatter into bucket order.
// ---------------------------------------------------------------------------
__global__ void scatter_kernel(const float4* __restrict__ posf4,
                               const int* __restrict__ bucketid,
                               int* __restrict__ off,
                               int* __restrict__ perm,
                               float4* __restrict__ posf4s, int total) {
  const int t = blockIdx.x * blockDim.x + threadIdx.x;
  if (t >= total) return;
  const int b = t >> 12;
  const int i = t & 4095;
  const int slot = atomicAdd(&off[b * NBUCK + bucketid[t]], 1);
  perm[b * 4096 + slot] = i;
  posf4s[b * 4096 + slot] = posf4[t];
}

// ---------------------------------------------------------------------------
// Kernel 1: kNN (proven round-4 version: 512 threads, float4 LDS, 72KB).
// ---------------------------------------------------------------------------
__global__ __launch_bounds__(512, 4) void knn_kernel(const float4* __restrict__ posf4s,
                                                     int* __restrict__ idx_out,
                                                     int N) {
  __shared__ float4 pts[4096];      // 64 KB: whole batch, staged once
  __shared__ float scrD[16 * 64];   // 4 KB: survivor distances (per query)
  __shared__ int   scrJ[16 * 64];   // 4 KB: survivor sorted-ids

  const int tid = threadIdx.x;
  const int lane = tid & 63;
  const int wid = tid >> 6;                 // 0..7
  const int qs0 = blockIdx.x * 16 + wid * 2;  // this wave's first query (sorted id)
  const int base = qs0 & ~4095;
  const int n0 = qs0 & 4095;                // batch-local sorted positions
  const int n1 = n0 + 1;
  const float4* pb = posf4s + base;

  // ---- stage the whole 4096-point batch into LDS (8 x 16B per thread) ----
  #pragma unroll
  for (int i = 0; i < 8; ++i) {
    const int c = wid * 8 + i;              // chunk 0..63, 64 points each
    __builtin_amdgcn_global_load_lds((gptr_t)(pb + c * 64 + lane),
                                     (lptr_t)&pts[c * 64], 16, 0, 0);
  }
  __syncthreads();

  const float4 qp0 = pts[n0];
  const float4 qp1 = pts[n1];

  // ---- scan (shared reads): per-lane minima for both queries ----
  float lmin0 = FINF, lmin1 = FINF;
  #pragma unroll 8
  for (int it = 0; it < 64; ++it) {
    const int j = (it << 6) + lane;
    const float4 p = pts[j];
    float dx = qp0.x - p.x, dy = qp0.y - p.y, dz = qp0.z - p.z;
    float d0 = dx * dx + dy * dy + dz * dz;
    dx = qp1.x - p.x; dy = qp1.y - p.y; dz = qp1.z - p.z;
    float d1 = dx * dx + dy * dy + dz * dz;
    if (j == n0) d0 = FINF;
    if (j == n1) d1 = FINF;
    lmin0 = fminf(lmin0, d0);
    lmin1 = fminf(lmin1, d1);
  }

  // ---- tau = 16th smallest lane-min (guarantees >=16 survivors).
  // Value-only bitonic, two queries interleaved for ILP. ----
  float a0 = lmin0, a1 = lmin1;
  #pragma unroll
  for (int k = 2; k <= 64; k <<= 1) {
    #pragma unroll
    for (int s = k >> 1; s > 0; s >>= 1) {
      const bool keepmin = (((lane & k) == 0) == ((lane & s) == 0));
      const float b0 = __shfl_xor(a0, s, 64);
      const float b1 = __shfl_xor(a1, s, 64);
      a0 = keepmin ? fminf(a0, b0) : fmaxf(a0, b0);
      a1 = keepmin ? fminf(a1, b1) : fmaxf(a1, b1);
    }
  }
  float tau0 = __shfl(a0, 15, 64);
  float tau1 = __shfl(a1, 15, 64);

  // ---- compaction (shared reads, recompute d): survivors -> LDS, cap 64 ----
  const unsigned long long lt = (1ull << lane) - 1ull;
  const int wq0 = wid * 2, wq1 = wid * 2 + 1;
  int cnt0 = 0, cnt1 = 0;
  #pragma unroll 4
  for (int it = 0; it < 64; ++it) {
    const int j = (it << 6) + lane;
    const float4 p = pts[j];
    float dx = qp0.x - p.x, dy = qp0.y - p.y, dz = qp0.z - p.z;
    float d0 = dx * dx + dy * dy + dz * dz;
    dx = qp1.x - p.x; dy = qp1.y - p.y; dz = qp1.z - p.z;
    float d1 = dx * dx + dy * dy + dz * dz;
    if (j == n0) d0 = FINF;
    if (j == n1) d1 = FINF;
    const bool p0 = (d0 <= tau0);
    const bool p1 = (d1 <= tau1);
    const unsigned long long m0 = __ballot(p0);
    const unsigned long long m1 = __ballot(p1);
    if (p0) {
      const int s0 = cnt0 + __popcll(m0 & lt);
      if (s0 < 64) { scrD[wq0 * 64 + s0] = d0; scrJ[wq0 * 64 + s0] = j; }
    }
    if (p1) {
      const int s1 = cnt1 + __popcll(m1 & lt);
      if (s1 < 64) { scrD[wq1 * 64 + s1] = d1; scrJ[wq1 * 64 + s1] = j; }
    }
    cnt0 += (int)__popcll(m0);
    cnt1 += (int)__popcll(m1);
  }

  // ---- per-query: sort survivors; rare retry tightens tau until cnt<=64 ----
  for (int q = 0; q < 2; ++q) {
    const int wq = wid * 2 + q;
    int cnt = q ? cnt1 : cnt0;
    float tau = q ? tau1 : tau0;
    const float4 qp = q ? qp1 : qp0;
    const int n = q ? n1 : n0;
    const int qs = qs0 + q;

    int m = cnt < 64 ? cnt : 64;
    float d = (lane < m) ? scrD[wq * 64 + lane] : FINF;
    int  jj = (lane < m) ? scrJ[wq * 64 + lane] : 0x40000000 + lane;
    bitonic64(d, jj, lane);

    while (cnt > 64) {
      // 16th smallest of 64 captured global elements -> valid tighter tau
      const float ntau = __shfl(d, 15, 64);
      if (!(ntau < tau)) break;   // degenerate exact-tie plateau: accept
      tau = ntau;
      cnt = 0;
      #pragma unroll 4
      for (int it = 0; it < 64; ++it) {
        const int j = (it << 6) + lane;
        const float4 p = pts[j];
        const float ddx = qp.x - p.x, ddy = qp.y - p.y, ddz = qp.z - p.z;
        float dd = ddx * ddx + ddy * ddy + ddz * ddz;
        if (j == n) dd = FINF;
        const bool pr = (dd <= tau);
        const unsigned long long mm = __ballot(pr);
        if (pr) {
          const int sl = cnt + __popcll(mm & lt);
          if (sl < 64) { scrD[wq * 64 + sl] = dd; scrJ[wq * 64 + sl] = j; }
        }
        cnt += (int)__popcll(mm);
      }
      m = cnt < 64 ? cnt : 64;
      d = (lane < m) ? scrD[wq * 64 + lane] : FINF;
      jj = (lane < m) ? scrJ[wq * 64 + lane] : 0x40000000 + lane;
      bitonic64(d, jj, lane);
    }

    if (lane < KNB) idx_out[(size_t)qs * KNB + lane] = jj;
  }
}

// ---------------------------------------------------------------------------
// Kernel 2: MERGED conv (feat + weights) — bf16-only (r12 verified).
// ---------------------------------------------------------------------------
__global__ __launch_bounds__(256) void conv_kernel(const float* __restrict__ src,
                                                   const int* __restrict__ perm,
                                                   unsigned short* __restrict__ dst,
                                                   const float* __restrict__ Wq,
                                                   const float* __restrict__ Wk,
                                                   const float* __restrict__ Wv,
                                                   const float* __restrict__ Wo,
                                                   unsigned short* __restrict__ BhQKV,
                                                   unsigned short* __restrict__ BhO) {
  const int b = blockIdx.x;
  if (b < 4096) {
    const int t = b * 256 + threadIdx.x;
    const int f = t * 4;
    const int row = f >> 9;
    const int col = f & 511;
    const int orig = (row & ~4095) + perm[row];
    const float4 v = *(const float4*)(src + (size_t)orig * 512 + col);
    ushort4 h;
    h.x = f2bf(v.x);
    h.y = f2bf(v.y);
    h.z = f2bf(v.z);
    h.w = f2bf(v.w);
    *(ushort4*)(dst + (size_t)row * 512 + col) = h;
  } else {
    const int bb = b - 4096;
    const int wsel = bb >> 10;
    const int i = ((bb & 1023) << 8) + threadIdx.x;
    const int n = i >> 9;
    const int k = i & 511;
    const float* wsrc = wsel == 0 ? Wq : wsel == 1 ? Wk : wsel == 2 ? Wv : Wo;
    unsigned short* dh = wsel < 3 ? BhQKV + (size_t)(wsel * 512 + n) * 512
                                  : BhO + (size_t)n * 512;
    dh[k] = f2bf(wsrc[(size_t)k * 512 + n]);
  }
}

// ---------------------------------------------------------------------------
// Kernel 3: bf16 MFMA GEMM (r12 verified schedule) — templated output dtype.
// ---------------------------------------------------------------------------
template <int OUT_BF16>
__global__ __launch_bounds__(256, 2) void gemm_bf16_kernel(
    const unsigned short* __restrict__ A,    // M x 512 bf16
    const unsigned short* __restrict__ B,    // Ncols x 512 bf16
    void* __restrict__ C0v, void* __restrict__ C1v, void* __restrict__ C2v,
    int nbn) {
  __shared__ unsigned short As[8192];   // 16 KB
  __shared__ unsigned short Bs[8192];   // 16 KB

  const int tid = threadIdx.x;
  const int wid = tid >> 6;
  const int lane = tid & 63;
  const int lm = lane & 15;
  const int kq = lane >> 4;
  const int wr = wid >> 1;
  const int wc = wid & 1;
  const int bid = blockIdx.x;
  const int xcd = bid & 7;
  const int i = bid >> 3;
  const int bm = xcd * 8 + i / nbn;
  const int bn = i % nbn;
  const int rowA0 = bm * 128;
  const int rowB0 = bn * 128;

  f32x4v acc[4][4];
  #pragma unroll
  for (int mi = 0; mi < 4; ++mi)
    #pragma unroll
    for (int ni = 0; ni < 4; ++ni) {
      f32x4v z = {0.f, 0.f, 0.f, 0.f};
      acc[mi][ni] = z;
    }

  auto stage64 = [&](unsigned short* dst, const unsigned short* gsrc,
                     int grow0, int gk0) {
    #pragma unroll
    for (int i2 = 0; i2 < 4; ++i2) {
      const int c = wid * 256 + i2 * 64 + lane;   // chunk 0..1023
      const int row = c >> 3;
      const int gq = (c & 7) ^ (row & 7);
      const unsigned short* ga =
          gsrc + (size_t)(grow0 + row) * 512 + gk0 + gq * 8;
      __builtin_amdgcn_global_load_lds((gptr_t)ga,
          (lptr_t)(dst + (size_t)(wid * 256 + i2 * 64) * 8), 16, 0, 0);
    }
  };
  auto rd64 = [&](const unsigned short* src, int row, int g) -> i32x4 {
    const int sl = row * 8 + (g ^ (row & 7));
    return *(const i32x4*)(src + (size_t)sl * 8);
  };

  // ---- prologue: stage tile k0=0 ----
  stage64(As, A, rowA0, 0);
  stage64(Bs, B, rowB0, 0);

  for (int k0 = 0; k0 < 512; k0 += 64) {
    __syncthreads();   // (a) stage landed (drains vmcnt), LDS consistent
    i32x4 ah[2][4], bb[2][4];
    #pragma unroll
    for (int kh = 0; kh < 2; ++kh) {
      const int g = kh * 4 + kq;
      #pragma unroll
      for (int mi = 0; mi < 4; ++mi)
        ah[kh][mi] = rd64(As, wr * 64 + mi * 16 + lm, g);
      #pragma unroll
      for (int ni = 0; ni < 4; ++ni)
        bb[kh][ni] = rd64(Bs, wc * 64 + ni * 16 + lm, g);
    }
    __syncthreads();   // (b) all waves done reading LDS

    if (k0 < 448) {
      stage64(As, A, rowA0, k0 + 64);
      stage64(Bs, B, rowB0, k0 + 64);
    }

    #pragma unroll
    for (int kh = 0; kh < 2; ++kh)
      #pragma unroll
      for (int mi = 0; mi < 4; ++mi)
        #pragma unroll
        for (int ni = 0; ni < 4; ++ni)
          acc[mi][ni] = __builtin_amdgcn_mfma_f32_16x16x32_bf16(
              __builtin_bit_cast(bf16x8v, ah[kh][mi]),
              __builtin_bit_cast(bf16x8v, bb[kh][ni]), acc[mi][ni], 0, 0, 0);
  }

  const int sel = bn >> 2;
  const int r0 = bm * 128 + wr * 64;
  const int c0 = ((bn & 3) << 7) + wc * 64;
  // C/D layout: col = lane&15, row = (lane>>4)*4 + reg   [m89/m91]
  if constexpr (OUT_BF16) {
    unsigned short* Cb = (unsigned short*)(sel == 0 ? C0v : sel == 1 ? C1v : C2v);
    #pragma unroll
    for (int mi = 0; mi < 4; ++mi)
      #pragma unroll
      for (int ni = 0; ni < 4; ++ni) {
        unsigned short* Cp =
            Cb + (size_t)(r0 + mi * 16 + kq * 4) * 512 + c0 + ni * 16 + lm;
        #pragma unroll
        for (int r = 0; r < 4; ++r) Cp[(size_t)r * 512] = f2bf(acc[mi][ni][r]);
      }
  } else {
    float* Cb = (float*)(sel == 0 ? C0v : sel == 1 ? C1v : C2v);
    #pragma unroll
    for (int mi = 0; mi < 4; ++mi)
      #pragma unroll
      for (int ni = 0; ni < 4; ++ni) {
        float* Cp = Cb + (size_t)(r0 + mi * 16 + kq * 4) * 512 + c0 + ni * 16 + lm;
        #pragma unroll
        for (int r = 0; r < 4; ++r) Cp[(size_t)r * 512] = acc[mi][ni][r];
      }
  }
}

// ---------------------------------------------------------------------------
// Kernel 4: local attention — Round 14: FULL GATHER HOIST. All 24 scattered
// 16B loads (np/kv/vv) depend only on nb; issue them together before any
// consumption, collapsing 4 serial VMEM rounds to 2. VGPR ~150-170 (plain
// launch_bounds(256), no min-wave pressure -> no forced spill). Arithmetic
// bit-identical to r13.
// ---------------------------------------------------------------------------
__global__ __launch_bounds__(256) void attn_kernel(const unsigned short* __restrict__ Q,
                                                   const unsigned short* __restrict__ Kb,
                                                   const unsigned short* __restrict__ Vb,
                                                   const int* __restrict__ idx,
                                                   const float4* __restrict__ posf4s,
                                                   const float* __restrict__ Wpos,
                                                   const float* __restrict__ bpos,
                                                   const float* __restrict__ temperature,
                                                   unsigned short* __restrict__ Aout,
                                                   int nblocks) {
  __shared__ float mS[4][8], sS[4][8];
  __shared__ float accHalf[2][512];   // half-B partial V-acc per query

  int bid = blockIdx.x;
  bid = (bid & 7) * (nblocks >> 3) + (bid >> 3);        // XCD-contiguous
  const int wid = threadIdx.x >> 6;
  const int lane = threadIdx.x & 63;
  const int qi = wid >> 1;            // query within block (0..1)
  const int hf = wid & 1;             // neighbor half (0..1)
  const int qs = bid * 2 + qi;
  const int s = lane & 7;
  const int grp = lane >> 3;          // head group (0..7)
  const int base = qs & ~4095;

  const float inv_t = 1.0f / temperature[0];

  float q[8];
  unpack8(*(const i32x4*)(Q + (size_t)qs * D_MODEL + lane * 8), q);

  const int* ip = idx + (size_t)qs * KNB + hf * 8;
  int nb[8];
  #pragma unroll
  for (int k = 0; k < 8; ++k) nb[k] = base + ip[k];   // sorted row

  // ---- ISSUE ALL GATHERS: 24 independent 16B loads in flight at once ----
  float4 np[8];
  i32x4 kv[8], vv[8];
  #pragma unroll
  for (int k = 0; k < 8; ++k) np[k] = posf4s[nb[k]];
  #pragma unroll
  for (int k = 0; k < 8; ++k)
    kv[k] = *(const i32x4*)(Kb + (size_t)nb[k] * D_MODEL + lane * 8);
  #pragma unroll
  for (int k = 0; k < 8; ++k)
    vv[k] = *(const i32x4*)(Vb + (size_t)nb[k] * D_MODEL + lane * 8);

  // ---- qw (uniform weights; broadcast loads hit L1) ----
  float wp[3][8], bp[8];
  #pragma unroll
  for (int c = 0; c < 3; ++c) {
    *(float4*)&wp[c][0] = *(const float4*)(Wpos + c * 128 + s * 8);
    *(float4*)&wp[c][4] = *(const float4*)(Wpos + c * 128 + s * 8 + 4);
  }
  *(float4*)&bp[0] = *(const float4*)(bpos + s * 8);
  *(float4*)&bp[4] = *(const float4*)(bpos + s * 8 + 4);
  float qw0 = 0.f, qw1 = 0.f, qw2 = 0.f, qb = 0.f;
  #pragma unroll
  for (int j = 0; j < 8; ++j) {
    qw0 += q[j] * wp[0][j];
    qw1 += q[j] * wp[1][j];
    qw2 += q[j] * wp[2][j];
    qb  += q[j] * bp[j];
  }
  #pragma unroll
  for (int off = 1; off < 8; off <<= 1) {
    qw0 += __shfl_xor(qw0, off, 64);
    qw1 += __shfl_xor(qw1, off, 64);
    qw2 += __shfl_xor(qw2, off, 64);
    qb  += __shfl_xor(qb, off, 64);
  }

  const float4 qp = posf4s[qs];

  // ---- pe from np ----
  float pe[8];
  #pragma unroll
  for (int k = 0; k < 8; ++k)
    pe[k] = qw0 * (qp.x - np[k].x) + qw1 * (qp.y - np[k].y) +
            qw2 * (qp.z - np[k].z) + qb;

  // ---- scores from kv ----
  float sc[8];
  #pragma unroll
  for (int k = 0; k < 8; ++k) {
    float kk[8];
    unpack8(kv[k], kk);
    float pdot = 0.f;
    #pragma unroll
    for (int j2 = 0; j2 < 8; ++j2) pdot += q[j2] * kk[j2];
    #pragma unroll
    for (int off = 1; off < 8; off <<= 1) pdot += __shfl_xor(pdot, off, 64);
    sc[k] = (pdot + pe[k]) * inv_t;
  }

  // ---- local softmax (this half, per head group) ----
  float m = sc[0];
  #pragma unroll
  for (int k = 1; k < 8; ++k) m = fmaxf(m, sc[k]);
  float ssum = 0.f;
  #pragma unroll
  for (int k = 0; k < 8; ++k) { sc[k] = expf(sc[k] - m); ssum += sc[k]; }

  // ---- local weighted V from vv ----
  float acc[8];
  #pragma unroll
  for (int j = 0; j < 8; ++j) acc[j] = 0.f;
  #pragma unroll
  for (int k = 0; k < 8; ++k) {
    float vf[8];
    unpack8(vv[k], vf);
    const float wk = sc[k];
    #pragma unroll
    for (int j = 0; j < 8; ++j) acc[j] += wk * vf[j];
  }

  // ---- 2-way online-softmax merge via LDS (PER HEAD GROUP) ----
  if ((lane & 7) == 0) { mS[wid][grp] = m; sS[wid][grp] = ssum; }
  if (hf == 1) {
    #pragma unroll
    for (int j = 0; j < 8; ++j) accHalf[qi][j * 64 + lane] = acc[j];
  }
  __syncthreads();
  if (hf == 0) {
    const float mB = mS[wid + 1][grp];
    const float sB = sS[wid + 1][grp];
    const float M = fmaxf(m, mB);
    const float wA = expf(m - M);
    const float wB = expf(mB - M);
    const float inv_s = 1.f / (ssum * wA + sB * wB);

    float a[8];
    #pragma unroll
    for (int j = 0; j < 8; ++j)
      a[j] = (acc[j] * wA + accHalf[qi][j * 64 + lane] * wB) * inv_s;

    ushort4 hi0, hi1;
    unsigned short* oh = Aout + (size_t)qs * 512 + lane * 8;
    hi0.x = f2bf(a[0]);
    hi0.y = f2bf(a[1]);
    hi0.z = f2bf(a[2]);
    hi0.w = f2bf(a[3]);
    hi1.x = f2bf(a[4]);
    hi1.y = f2bf(a[5]);
    hi1.z = f2bf(a[6]);
    hi1.w = f2bf(a[7]);
    *(ushort4*)(oh) = hi0;
    *(ushort4*)(oh + 4) = hi1;
  }
}

// ---------------------------------------------------------------------------
// Kernel 5: LN over sorted proj rows, un-permuting on the final write.
// ---------------------------------------------------------------------------
__global__ __launch_bounds__(256) void ln_kernel(const float* __restrict__ proj,
                                                 const float* __restrict__ feat,
                                                 const int* __restrict__ perm,
                                                 const float* __restrict__ bo,
                                                 const float* __restrict__ gamma,
                                                 const float* __restrict__ beta,
                                                 float* __restrict__ out) {
  const int row = blockIdx.x * 4 + (threadIdx.x >> 6);
  const int lane = threadIdx.x & 63;
  const int orig = (row & ~4095) + perm[row];
  const float* pr = proj + (size_t)row * D_MODEL;
  const float* fr = feat + (size_t)orig * D_MODEL;

  float x[8];
  #pragma unroll
  for (int u = 0; u < 2; ++u) {
    const int c = u * 256 + lane * 4;
    const float4 p = *(const float4*)(pr + c);
    const float4 f = *(const float4*)(fr + c);
    const float4 bb = *(const float4*)(bo + c);
    x[u * 4 + 0] = p.x + bb.x + f.x;
    x[u * 4 + 1] = p.y + bb.y + f.y;
    x[u * 4 + 2] = p.z + bb.z + f.z;
    x[u * 4 + 3] = p.w + bb.w + f.w;
  }
  float sum = 0.f, sumsq = 0.f;
  #pragma unroll
  for (int i = 0; i < 8; ++i) { sum += x[i]; sumsq += x[i] * x[i]; }
  sum = wave_reduce_sum(sum);
  sumsq = wave_reduce_sum(sumsq);
  const float mu = sum * (1.f / D_MODEL);
  const float var = sumsq * (1.f / D_MODEL) - mu * mu;
  const float rstd = rsqrtf(var + LN_EPS);

  #pragma unroll
  for (int u = 0; u < 2; ++u) {
    const int c = u * 256 + lane * 4;
    const float4 g = *(const float4*)(gamma + c);
    const float4 bt = *(const float4*)(beta + c);
    float4 o;
    o.x = (x[u * 4 + 0] - mu) * rstd * g.x + bt.x;
    o.y = (x[u * 4 + 1] - mu) * rstd * g.y + bt.y;
    o.z = (x[u * 4 + 2] - mu) * rstd * g.z + bt.z;
    o.w = (x[u * 4 + 3] - mu) * rstd * g.w + bt.w;
    *(float4*)(out + (size_t)orig * D_MODEL + c) = o;
  }
}

// ---------------------------------------------------------------------------
extern "C" void kernel_launch(void* const* d_in, const int* in_sizes, int n_in,
                              void* d_out, int out_size, void* d_ws, size_t ws_size,
                              hipStream_t stream) {
  const float* positions = (const float*)d_in[0];
  const float* features  = (const float*)d_in[1];
  const float* Wq   = (const float*)d_in[3];
  const float* Wk   = (const float*)d_in[4];
  const float* Wv   = (const float*)d_in[5];
  const float* Wo   = (const float*)d_in[6];
  const float* bo   = (const float*)d_in[7];
  const float* Wpos = (const float*)d_in[8];
  const float* bpos = (const float*)d_in[9];
  const float* temp = (const float*)d_in[10];
  const float* gamma = (const float*)d_in[11];
  const float* beta  = (const float*)d_in[12];

  const int B = 2, N = 4096;
  const int BN = B * N;

  char* w = (char*)d_ws;
  float4* posf4  = (float4*)w;             w += (size_t)BN * sizeof(float4);
  float4* posf4s = (float4*)w;             w += (size_t)BN * sizeof(float4);
  int*    idxb   = (int*)w;                w += (size_t)BN * KNB * sizeof(int);
  int*    permb  = (int*)w;                w += (size_t)BN * sizeof(int);
  int*    histb  = (int*)w;                w += (size_t)B * NBUCK * sizeof(int);
  int*    offb   = (int*)w;                w += (size_t)B * NBUCK * sizeof(int);
  int*    buckb  = (int*)w;                w += (size_t)BN * sizeof(int);
  unsigned short* Abuf = (unsigned short*)w; w += (size_t)BN * 512 * 2;
  unsigned short* BhQKV = (unsigned short*)w; w += (size_t)1536 * 512 * 2;
  unsigned short* BhO = (unsigned short*)w;   w += (size_t)512 * 512 * 2;
  unsigned short* Qb16 = (unsigned short*)w;  w += (size_t)BN * 512 * 2;   // 8 MB
  unsigned short* Kb16 = (unsigned short*)w;  w += (size_t)BN * 512 * 2;   // 8 MB
  unsigned short* Vb16 = (unsigned short*)d_out;   // 8 MB of out; dead before LN
  float* projb = (float*)Qb16;             // 16 MB overlays Qb16+Kb16 (dead)

  zero_hist_kernel<<<(B * NBUCK + 255) / 256, 256, 0, stream>>>(histb, B * NBUCK);
  bucket_kernel<<<(BN + 255) / 256, 256, 0, stream>>>(positions, posf4, histb,
                                                      buckb, BN);
  scan_kernel<<<B, 1024, 0, stream>>>(histb, offb);
  scatter_kernel<<<(BN + 255) / 256, 256, 0, stream>>>(posf4, buckb, offb,
                                                       permb, posf4s, BN);
  knn_kernel<<<BN / 16, 512, 0, stream>>>(posf4s, idxb, N);

  conv_kernel<<<8192, 256, 0, stream>>>(features, permb, Abuf,
                                        Wq, Wk, Wv, Wo, BhQKV, BhO);

  gemm_bf16_kernel<1><<<768, 256, 0, stream>>>(
      Abuf, BhQKV, Qb16, Kb16, Vb16, 12);

  attn_kernel<<<BN / 2, 256, 0, stream>>>(Qb16, Kb16, Vb16, idxb,
                                          posf4s, Wpos, bpos, temp, Abuf,
                                          BN / 2);

  gemm_bf16_kernel<0><<<256, 256, 0, stream>>>(
      Abuf, BhO, projb, projb, projb, 4);

  ln_kernel<<<BN / 4, 256, 0, stream>>>(projb, features, permb, bo, gamma, beta,
                                        (float*)d_out);
}

// Round 16
// 197.509 us; speedup vs baseline: 1.2623x; 1.0026x over previous
//
#include <hip/hip_runtime.h>
#include <cstdint>

#define D_MODEL 512
#define NUM_HEADS 8
#define D_HEAD 64
#define KNB 16
#define NBUCK 2048
#define LN_EPS 1e-5f
#define FINF 3.4e38f

typedef __bf16 bf16x8v __attribute__((ext_vector_type(8)));
typedef float f32x4v __attribute__((ext_vector_type(4)));
typedef int i32x4 __attribute__((ext_vector_type(4)));
typedef const __attribute__((address_space(1))) unsigned int* gptr_t;
typedef __attribute__((address_space(3))) unsigned int* lptr_t;

__device__ __forceinline__ float wave_reduce_sum(float v) {
  #pragma unroll
  for (int off = 32; off > 0; off >>= 1) v += __shfl_xor(v, off, 64);
  return v;
}

// bf16 helpers (bit-level, round-to-nearest-even)
__device__ __forceinline__ unsigned short f2bf(float x) {
  unsigned int u = __float_as_uint(x);
  u = (u + 0x7fffu + ((u >> 16) & 1u)) >> 16;
  return (unsigned short)u;
}
__device__ __forceinline__ float bf2f(unsigned short h) {
  return __uint_as_float(((unsigned int)h) << 16);
}
// unpack 8 bf16 (one 16B vector) to 8 floats: 2 bit-ops per pair.
__device__ __forceinline__ void unpack8(i32x4 v, float* o) {
  #pragma unroll
  for (int i = 0; i < 4; ++i) {
    const unsigned u = (unsigned)v[i];
    o[2 * i]     = __uint_as_float(u << 16);
    o[2 * i + 1] = __uint_as_float(u & 0xffff0000u);
  }
}

// Morton helpers: bucketing quality only affects SPEED.
__device__ __forceinline__ unsigned spread3(unsigned x) {
  x &= 0x3FFu;
  x = (x | (x << 16)) & 0x030000FFu;
  x = (x | (x << 8))  & 0x0300F00Fu;
  x = (x | (x << 4))  & 0x030C30C3u;
  x = (x | (x << 2))  & 0x09249249u;
  return x;
}
__device__ __forceinline__ unsigned quant10(float v) {
  int q = (int)((v + 6.f) * (1023.f / 12.f));
  q = q < 0 ? 0 : (q > 1023 ? 1023 : q);
  return (unsigned)q;
}

// 64-lane bitonic sort ascending by (d, j) lexicographic (pairs distinct).
__device__ __forceinline__ void bitonic64(float& d, int& j, int lane) {
  #pragma unroll
  for (int k = 2; k <= 64; k <<= 1) {
    #pragma unroll
    for (int s = k >> 1; s > 0; s >>= 1) {
      const float od = __shfl_xor(d, s, 64);
      const int   oj = __shfl_xor(j, s, 64);
      const bool up = ((lane & k) == 0);
      const bool lower = ((lane & s) == 0);
      const bool oless = (od < d) || (od == d && oj < j);
      if ((lower == up) ? oless : !oless) { d = od; j = oj; }
    }
  }
}

// ---------------------------------------------------------------------------
// Kernel 0b: pad pos -> float4, Morton bucket (top 11 bits), histogram.
// (hist zeroed via hipMemsetAsync in the launcher.)
// ---------------------------------------------------------------------------
__global__ void bucket_kernel(const float* __restrict__ pos,
                              float4* __restrict__ posf4,
                              int* __restrict__ hist,
                              int* __restrict__ bucketid, int total) {
  const int t = blockIdx.x * blockDim.x + threadIdx.x;
  if (t >= total) return;
  const float4 p = make_float4(pos[t * 3], pos[t * 3 + 1], pos[t * 3 + 2], 0.f);
  posf4[t] = p;
  const unsigned code = (spread3(quant10(p.z)) << 2) |
                        (spread3(quant10(p.y)) << 1) | spread3(quant10(p.x));
  const int bk = code >> 19;
  const int b = t >> 12;
  bucketid[t] = bk;
  atomicAdd(&hist[b * NBUCK + bk], 1);
}

// ---------------------------------------------------------------------------
// Kernel 0c: exclusive scan of 2048 buckets per batch (one block per batch).
// ---------------------------------------------------------------------------
__global__ __launch_bounds__(1024) void scan_kernel(const int* __restrict__ hist,
                                                    int* __restrict__ off) {
  __shared__ int lsum[16];
  const int b = blockIdx.x;
  const int tid = threadIdx.x;
  const int lane = tid & 63, wv = tid >> 6;
  const int h0 = hist[b * NBUCK + 2 * tid];
  const int h1 = hist[b * NBUCK + 2 * tid + 1];
  int v = h0 + h1;
  #pragma unroll
  for (int d = 1; d < 64; d <<= 1) {
    const int u = __shfl_up(v, d, 64);
    if (lane >= d) v += u;
  }
  if (lane == 63) lsum[wv] = v;
  __syncthreads();
  if (wv == 0) {
    int s = (lane < 16) ? lsum[lane] : 0;
    #pragma unroll
    for (int d = 1; d < 16; d <<= 1) {
      const int u = __shfl_up(s, d, 64);
      if (lane >= d) s += u;
    }
    if (lane < 16) lsum[lane] = s;
  }
  __syncthreads();
  const int base = (wv > 0) ? lsum[wv - 1] : 0;
  const int excl = v + base - (h0 + h1);
  off[b * NBUCK + 2 * tid] = excl;
  off[b * NBUCK + 2 * tid + 1] = excl + h0;
}

// ---------------------------------------------------------------------------
// Kernel 0d: scatter into bucket order.
// ---------------------------------------------------------------------------
__global__ void scatter_kernel(const float4* __restrict__ posf4,
                               const int* __restrict__ bucketid,
                               int* __restrict__ off,
                               int* __restrict__ perm,
                               float4* __restrict__ posf4s, int total) {
  const int t = blockIdx.x * blockDim.x + threadIdx.x;
  if (t >= total) return;
  const int b = t >> 12;
  const int i = t & 4095;
  const int slot = atomicAdd(&off[b * NBUCK + bucketid[t]], 1);
  perm[b * 4096 + slot] = i;
  posf4s[b * 4096 + slot] = posf4[t];
}

// ---------------------------------------------------------------------------
// Kernel 1: kNN — REVERTED to the round-14 proven full-scan version (the
// r15 Morton-window tau coincided with a core-dump failure; unprovable,
// shelved). 512 threads, float4 LDS, 72KB, 2 queries/wave.
// ---------------------------------------------------------------------------
__global__ __launch_bounds__(512, 4) void knn_kernel(const float4* __restrict__ posf4s,
                                                     int* __restrict__ idx_out,
                                                     int N) {
  __shared__ float4 pts[4096];      // 64 KB: whole batch, staged once
  __shared__ float scrD[16 * 64];   // 4 KB: survivor distances (per query)
  __shared__ int   scrJ[16 * 64];   // 4 KB: survivor sorted-ids

  const int tid = threadIdx.x;
  const int lane = tid & 63;
  const int wid = tid >> 6;                 // 0..7
  const int qs0 = blockIdx.x * 16 + wid * 2;  // this wave's first query (sorted id)
  const int base = qs0 & ~4095;
  const int n0 = qs0 & 4095;                // batch-local sorted positions
  const int n1 = n0 + 1;
  const float4* pb = posf4s + base;

  // ---- stage the whole 4096-point batch into LDS (8 x 16B per thread) ----
  #pragma unroll
  for (int i = 0; i < 8; ++i) {
    const int c = wid * 8 + i;              // chunk 0..63, 64 points each
    __builtin_amdgcn_global_load_lds((gptr_t)(pb + c * 64 + lane),
                                     (lptr_t)&pts[c * 64], 16, 0, 0);
  }
  __syncthreads();

  const float4 qp0 = pts[n0];
  const float4 qp1 = pts[n1];

  // ---- scan (shared reads): per-lane minima for both queries ----
  float lmin0 = FINF, lmin1 = FINF;
  #pragma unroll 8
  for (int it = 0; it < 64; ++it) {
    const int j = (it << 6) + lane;
    const float4 p = pts[j];
    float dx = qp0.x - p.x, dy = qp0.y - p.y, dz = qp0.z - p.z;
    float d0 = dx * dx + dy * dy + dz * dz;
    dx = qp1.x - p.x; dy = qp1.y - p.y; dz = qp1.z - p.z;
    float d1 = dx * dx + dy * dy + dz * dz;
    if (j == n0) d0 = FINF;
    if (j == n1) d1 = FINF;
    lmin0 = fminf(lmin0, d0);
    lmin1 = fminf(lmin1, d1);
  }

  // ---- tau = 16th smallest lane-min (guarantees >=16 survivors).
  // Value-only bitonic, two queries interleaved for ILP. ----
  float a0 = lmin0, a1 = lmin1;
  #pragma unroll
  for (int k = 2; k <= 64; k <<= 1) {
    #pragma unroll
    for (int s = k >> 1; s > 0; s >>= 1) {
      const bool keepmin = (((lane & k) == 0) == ((lane & s) == 0));
      const float b0 = __shfl_xor(a0, s, 64);
      const float b1 = __shfl_xor(a1, s, 64);
      a0 = keepmin ? fminf(a0, b0) : fmaxf(a0, b0);
      a1 = keepmin ? fminf(a1, b1) : fmaxf(a1, b1);
    }
  }
  float tau0 = __shfl(a0, 15, 64);
  float tau1 = __shfl(a1, 15, 64);

  // ---- compaction (shared reads, recompute d): survivors -> LDS, cap 64 ----
  const unsigned long long lt = (1ull << lane) - 1ull;
  const int wq0 = wid * 2, wq1 = wid * 2 + 1;
  int cnt0 = 0, cnt1 = 0;
  #pragma unroll 4
  for (int it = 0; it < 64; ++it) {
    const int j = (it << 6) + lane;
    const float4 p = pts[j];
    float dx = qp0.x - p.x, dy = qp0.y - p.y, dz = qp0.z - p.z;
    float d0 = dx * dx + dy * dy + dz * dz;
    dx = qp1.x - p.x; dy = qp1.y - p.y; dz = qp1.z - p.z;
    float d1 = dx * dx + dy * dy + dz * dz;
    if (j == n0) d0 = FINF;
    if (j == n1) d1 = FINF;
    const bool p0 = (d0 <= tau0);
    const bool p1 = (d1 <= tau1);
    const unsigned long long m0 = __ballot(p0);
    const unsigned long long m1 = __ballot(p1);
    if (p0) {
      const int s0 = cnt0 + __popcll(m0 & lt);
      if (s0 < 64) { scrD[wq0 * 64 + s0] = d0; scrJ[wq0 * 64 + s0] = j; }
    }
    if (p1) {
      const int s1 = cnt1 + __popcll(m1 & lt);
      if (s1 < 64) { scrD[wq1 * 64 + s1] = d1; scrJ[wq1 * 64 + s1] = j; }
    }
    cnt0 += (int)__popcll(m0);
    cnt1 += (int)__popcll(m1);
  }

  // ---- per-query: sort survivors; rare retry tightens tau until cnt<=64 ----
  for (int q = 0; q < 2; ++q) {
    const int wq = wid * 2 + q;
    int cnt = q ? cnt1 : cnt0;
    float tau = q ? tau1 : tau0;
    const float4 qp = q ? qp1 : qp0;
    const int n = q ? n1 : n0;
    const int qs = qs0 + q;

    int m = cnt < 64 ? cnt : 64;
    float d = (lane < m) ? scrD[wq * 64 + lane] : FINF;
    int  jj = (lane < m) ? scrJ[wq * 64 + lane] : 0x40000000 + lane;
    bitonic64(d, jj, lane);

    while (cnt > 64) {
      // 16th smallest of 64 captured global elements -> valid tighter tau
      const float ntau = __shfl(d, 15, 64);
      if (!(ntau < tau)) break;   // degenerate exact-tie plateau: accept
      tau = ntau;
      cnt = 0;
      #pragma unroll 4
      for (int it = 0; it < 64; ++it) {
        const int j = (it << 6) + lane;
        const float4 p = pts[j];
        const float ddx = qp.x - p.x, ddy = qp.y - p.y, ddz = qp.z - p.z;
        float dd = ddx * ddx + ddy * ddy + ddz * ddz;
        if (j == n) dd = FINF;
        const bool pr = (dd <= tau);
        const unsigned long long mm = __ballot(pr);
        if (pr) {
          const int sl = cnt + __popcll(mm & lt);
          if (sl < 64) { scrD[wq * 64 + sl] = dd; scrJ[wq * 64 + sl] = j; }
        }
        cnt += (int)__popcll(mm);
      }
      m = cnt < 64 ? cnt : 64;
      d = (lane < m) ? scrD[wq * 64 + lane] : FINF;
      jj = (lane < m) ? scrJ[wq * 64 + lane] : 0x40000000 + lane;
      bitonic64(d, jj, lane);
    }

    if (lane < KNB) idx_out[(size_t)qs * KNB + lane] = jj;
  }
}

// ---------------------------------------------------------------------------
// Kernel 2: MERGED conv (feat + weights) — bf16-only (r12 verified).
// ---------------------------------------------------------------------------
__global__ __launch_bounds__(256) void conv_kernel(const float* __restrict__ src,
                                                   const int* __restrict__ perm,
                                                   unsigned short* __restrict__ dst,
                                                   const float* __restrict__ Wq,
                                                   const float* __restrict__ Wk,
                                                   const float* __restrict__ Wv,
                                                   const float* __restrict__ Wo,
                                                   unsigned short* __restrict__ BhQKV,
                                                   unsigned short* __restrict__ BhO) {
  const int b = blockIdx.x;
  if (b < 4096) {
    const int t = b * 256 + threadIdx.x;
    const int f = t * 4;
    const int row = f >> 9;
    const int col = f & 511;
    const int orig = (row & ~4095) + perm[row];
    const float4 v = *(const float4*)(src + (size_t)orig * 512 + col);
    ushort4 h;
    h.x = f2bf(v.x);
    h.y = f2bf(v.y);
    h.z = f2bf(v.z);
    h.w = f2bf(v.w);
    *(ushort4*)(dst + (size_t)row * 512 + col) = h;
  } else {
    const int bb = b - 4096;
    const int wsel = bb >> 10;
    const int i = ((bb & 1023) << 8) + threadIdx.x;
    const int n = i >> 9;
    const int k = i & 511;
    const float* wsrc = wsel == 0 ? Wq : wsel == 1 ? Wk : wsel == 2 ? Wv : Wo;
    unsigned short* dh = wsel < 3 ? BhQKV + (size_t)(wsel * 512 + n) * 512
                                  : BhO + (size_t)n * 512;
    dh[k] = f2bf(wsrc[(size_t)k * 512 + n]);
  }
}

// ---------------------------------------------------------------------------
// Kernel 3: bf16 MFMA GEMM (r12 verified schedule) — templated output dtype.
// ---------------------------------------------------------------------------
template <int OUT_BF16>
__global__ __launch_bounds__(256, 2) void gemm_bf16_kernel(
    const unsigned short* __restrict__ A,    // M x 512 bf16
    const unsigned short* __restrict__ B,    // Ncols x 512 bf16
    void* __restrict__ C0v, void* __restrict__ C1v, void* __restrict__ C2v,
    int nbn) {
  __shared__ unsigned short As[8192];   // 16 KB
  __shared__ unsigned short Bs[8192];   // 16 KB

  const int tid = threadIdx.x;
  const int wid = tid >> 6;
  const int lane = tid & 63;
  const int lm = lane & 15;
  const int kq = lane >> 4;
  const int wr = wid >> 1;
  const int wc = wid & 1;
  const int bid = blockIdx.x;
  const int xcd = bid & 7;
  const int i = bid >> 3;
  const int bm = xcd * 8 + i / nbn;
  const int bn = i % nbn;
  const int rowA0 = bm * 128;
  const int rowB0 = bn * 128;

  f32x4v acc[4][4];
  #pragma unroll
  for (int mi = 0; mi < 4; ++mi)
    #pragma unroll
    for (int ni = 0; ni < 4; ++ni) {
      f32x4v z = {0.f, 0.f, 0.f, 0.f};
      acc[mi][ni] = z;
    }

  auto stage64 = [&](unsigned short* dst, const unsigned short* gsrc,
                     int grow0, int gk0) {
    #pragma unroll
    for (int i2 = 0; i2 < 4; ++i2) {
      const int c = wid * 256 + i2 * 64 + lane;   // chunk 0..1023
      const int row = c >> 3;
      const int gq = (c & 7) ^ (row & 7);
      const unsigned short* ga =
          gsrc + (size_t)(grow0 + row) * 512 + gk0 + gq * 8;
      __builtin_amdgcn_global_load_lds((gptr_t)ga,
          (lptr_t)(dst + (size_t)(wid * 256 + i2 * 64) * 8), 16, 0, 0);
    }
  };
  auto rd64 = [&](const unsigned short* src, int row, int g) -> i32x4 {
    const int sl = row * 8 + (g ^ (row & 7));
    return *(const i32x4*)(src + (size_t)sl * 8);
  };

  // ---- prologue: stage tile k0=0 ----
  stage64(As, A, rowA0, 0);
  stage64(Bs, B, rowB0, 0);

  for (int k0 = 0; k0 < 512; k0 += 64) {
    __syncthreads();   // (a) stage landed (drains vmcnt), LDS consistent
    i32x4 ah[2][4], bb[2][4];
    #pragma unroll
    for (int kh = 0; kh < 2; ++kh) {
      const int g = kh * 4 + kq;
      #pragma unroll
      for (int mi = 0; mi < 4; ++mi)
        ah[kh][mi] = rd64(As, wr * 64 + mi * 16 + lm, g);
      #pragma unroll
      for (int ni = 0; ni < 4; ++ni)
        bb[kh][ni] = rd64(Bs, wc * 64 + ni * 16 + lm, g);
    }
    __syncthreads();   // (b) all waves done reading LDS

    if (k0 < 448) {
      stage64(As, A, rowA0, k0 + 64);
      stage64(Bs, B, rowB0, k0 + 64);
    }

    #pragma unroll
    for (int kh = 0; kh < 2; ++kh)
      #pragma unroll
      for (int mi = 0; mi < 4; ++mi)
        #pragma unroll
        for (int ni = 0; ni < 4; ++ni)
          acc[mi][ni] = __builtin_amdgcn_mfma_f32_16x16x32_bf16(
              __builtin_bit_cast(bf16x8v, ah[kh][mi]),
              __builtin_bit_cast(bf16x8v, bb[kh][ni]), acc[mi][ni], 0, 0, 0);
  }

  const int sel = bn >> 2;
  const int r0 = bm * 128 + wr * 64;
  const int c0 = ((bn & 3) << 7) + wc * 64;
  // C/D layout: col = lane&15, row = (lane>>4)*4 + reg   [m89/m91]
  if constexpr (OUT_BF16) {
    unsigned short* Cb = (unsigned short*)(sel == 0 ? C0v : sel == 1 ? C1v : C2v);
    #pragma unroll
    for (int mi = 0; mi < 4; ++mi)
      #pragma unroll
      for (int ni = 0; ni < 4; ++ni) {
        unsigned short* Cp =
            Cb + (size_t)(r0 + mi * 16 + kq * 4) * 512 + c0 + ni * 16 + lm;
        #pragma unroll
        for (int r = 0; r < 4; ++r) Cp[(size_t)r * 512] = f2bf(acc[mi][ni][r]);
      }
  } else {
    float* Cb = (float*)(sel == 0 ? C0v : sel == 1 ? C1v : C2v);
    #pragma unroll
    for (int mi = 0; mi < 4; ++mi)
      #pragma unroll
      for (int ni = 0; ni < 4; ++ni) {
        float* Cp = Cb + (size_t)(r0 + mi * 16 + kq * 4) * 512 + c0 + ni * 16 + lm;
        #pragma unroll
        for (int r = 0; r < 4; ++r) Cp[(size_t)r * 512] = acc[mi][ni][r];
      }
  }
}

// ---------------------------------------------------------------------------
// Kernel 4: local attention — full gather hoist (r14 verified).
// ---------------------------------------------------------------------------
__global__ __launch_bounds__(256) void attn_kernel(const unsigned short* __restrict__ Q,
                                                   const unsigned short* __restrict__ Kb,
                                                   const unsigned short* __restrict__ Vb,
                                                   const int* __restrict__ idx,
                                                   const float4* __restrict__ posf4s,
                                                   const float* __restrict__ Wpos,
                                                   const float* __restrict__ bpos,
                                                   const float* __restrict__ temperature,
                                                   unsigned short* __restrict__ Aout,
                                                   int nblocks) {
  __shared__ float mS[4][8], sS[4][8];
  __shared__ float accHalf[2][512];   // half-B partial V-acc per query

  int bid = blockIdx.x;
  bid = (bid & 7) * (nblocks >> 3) + (bid >> 3);        // XCD-contiguous
  const int wid = threadIdx.x >> 6;
  const int lane = threadIdx.x & 63;
  const int qi = wid >> 1;            // query within block (0..1)
  const int hf = wid & 1;             // neighbor half (0..1)
  const int qs = bid * 2 + qi;
  const int s = lane & 7;
  const int grp = lane >> 3;          // head group (0..7)
  const int base = qs & ~4095;

  const float inv_t = 1.0f / temperature[0];

  float q[8];
  unpack8(*(const i32x4*)(Q + (size_t)qs * D_MODEL + lane * 8), q);

  const int* ip = idx + (size_t)qs * KNB + hf * 8;
  int nb[8];
  #pragma unroll
  for (int k = 0; k < 8; ++k) nb[k] = base + ip[k];   // sorted row

  // ---- ISSUE ALL GATHERS: 24 independent 16B loads in flight at once ----
  float4 np[8];
  i32x4 kv[8], vv[8];
  #pragma unroll
  for (int k = 0; k < 8; ++k) np[k] = posf4s[nb[k]];
  #pragma unroll
  for (int k = 0; k < 8; ++k)
    kv[k] = *(const i32x4*)(Kb + (size_t)nb[k] * D_MODEL + lane * 8);
  #pragma unroll
  for (int k = 0; k < 8; ++k)
    vv[k] = *(const i32x4*)(Vb + (size_t)nb[k] * D_MODEL + lane * 8);

  // ---- qw (uniform weights; broadcast loads hit L1) ----
  float wp[3][8], bp[8];
  #pragma unroll
  for (int c = 0; c < 3; ++c) {
    *(float4*)&wp[c][0] = *(const float4*)(Wpos + c * 128 + s * 8);
    *(float4*)&wp[c][4] = *(const float4*)(Wpos + c * 128 + s * 8 + 4);
  }
  *(float4*)&bp[0] = *(const float4*)(bpos + s * 8);
  *(float4*)&bp[4] = *(const float4*)(bpos + s * 8 + 4);
  float qw0 = 0.f, qw1 = 0.f, qw2 = 0.f, qb = 0.f;
  #pragma unroll
  for (int j = 0; j < 8; ++j) {
    qw0 += q[j] * wp[0][j];
    qw1 += q[j] * wp[1][j];
    qw2 += q[j] * wp[2][j];
    qb  += q[j] * bp[j];
  }
  #pragma unroll
  for (int off = 1; off < 8; off <<= 1) {
    qw0 += __shfl_xor(qw0, off, 64);
    qw1 += __shfl_xor(qw1, off, 64);
    qw2 += __shfl_xor(qw2, off, 64);
    qb  += __shfl_xor(qb, off, 64);
  }

  const float4 qp = posf4s[qs];

  // ---- pe from np ----
  float pe[8];
  #pragma unroll
  for (int k = 0; k < 8; ++k)
    pe[k] = qw0 * (qp.x - np[k].x) + qw1 * (qp.y - np[k].y) +
            qw2 * (qp.z - np[k].z) + qb;

  // ---- scores from kv ----
  float sc[8];
  #pragma unroll
  for (int k = 0; k < 8; ++k) {
    float kk[8];
    unpack8(kv[k], kk);
    float pdot = 0.f;
    #pragma unroll
    for (int j2 = 0; j2 < 8; ++j2) pdot += q[j2] * kk[j2];
    #pragma unroll
    for (int off = 1; off < 8; off <<= 1) pdot += __shfl_xor(pdot, off, 64);
    sc[k] = (pdot + pe[k]) * inv_t;
  }

  // ---- local softmax (this half, per head group) ----
  float m = sc[0];
  #pragma unroll
  for (int k = 1; k < 8; ++k) m = fmaxf(m, sc[k]);
  float ssum = 0.f;
  #pragma unroll
  for (int k = 0; k < 8; ++k) { sc[k] = expf(sc[k] - m); ssum += sc[k]; }

  // ---- local weighted V from vv ----
  float acc[8];
  #pragma unroll
  for (int j = 0; j < 8; ++j) acc[j] = 0.f;
  #pragma unroll
  for (int k = 0; k < 8; ++k) {
    float vf[8];
    unpack8(vv[k], vf);
    const float wk = sc[k];
    #pragma unroll
    for (int j = 0; j < 8; ++j) acc[j] += wk * vf[j];
  }

  // ---- 2-way online-softmax merge via LDS (PER HEAD GROUP) ----
  if ((lane & 7) == 0) { mS[wid][grp] = m; sS[wid][grp] = ssum; }
  if (hf == 1) {
    #pragma unroll
    for (int j = 0; j < 8; ++j) accHalf[qi][j * 64 + lane] = acc[j];
  }
  __syncthreads();
  if (hf == 0) {
    const float mB = mS[wid + 1][grp];
    const float sB = sS[wid + 1][grp];
    const float M = fmaxf(m, mB);
    const float wA = expf(m - M);
    const float wB = expf(mB - M);
    const float inv_s = 1.f / (ssum * wA + sB * wB);

    float a[8];
    #pragma unroll
    for (int j = 0; j < 8; ++j)
      a[j] = (acc[j] * wA + accHalf[qi][j * 64 + lane] * wB) * inv_s;

    ushort4 hi0, hi1;
    unsigned short* oh = Aout + (size_t)qs * 512 + lane * 8;
    hi0.x = f2bf(a[0]);
    hi0.y = f2bf(a[1]);
    hi0.z = f2bf(a[2]);
    hi0.w = f2bf(a[3]);
    hi1.x = f2bf(a[4]);
    hi1.y = f2bf(a[5]);
    hi1.z = f2bf(a[6]);
    hi1.w = f2bf(a[7]);
    *(ushort4*)(oh) = hi0;
    *(ushort4*)(oh + 4) = hi1;
  }
}

// ---------------------------------------------------------------------------
// Kernel 5: LN over sorted proj rows, un-permuting on the final write.
// ---------------------------------------------------------------------------
__global__ __launch_bounds__(256) void ln_kernel(const float* __restrict__ proj,
                                                 const float* __restrict__ feat,
                                                 const int* __restrict__ perm,
                                                 const float* __restrict__ bo,
                                                 const float* __restrict__ gamma,
                                                 const float* __restrict__ beta,
                                                 float* __restrict__ out) {
  const int row = blockIdx.x * 4 + (threadIdx.x >> 6);
  const int lane = threadIdx.x & 63;
  const int orig = (row & ~4095) + perm[row];
  const float* pr = proj + (size_t)row * D_MODEL;
  const float* fr = feat + (size_t)orig * D_MODEL;

  float x[8];
  #pragma unroll
  for (int u = 0; u < 2; ++u) {
    const int c = u * 256 + lane * 4;
    const float4 p = *(const float4*)(pr + c);
    const float4 f = *(const float4*)(fr + c);
    const float4 bb = *(const float4*)(bo + c);
    x[u * 4 + 0] = p.x + bb.x + f.x;
    x[u * 4 + 1] = p.y + bb.y + f.y;
    x[u * 4 + 2] = p.z + bb.z + f.z;
    x[u * 4 + 3] = p.w + bb.w + f.w;
  }
  float sum = 0.f, sumsq = 0.f;
  #pragma unroll
  for (int i = 0; i < 8; ++i) { sum += x[i]; sumsq += x[i] * x[i]; }
  sum = wave_reduce_sum(sum);
  sumsq = wave_reduce_sum(sumsq);
  const float mu = sum * (1.f / D_MODEL);
  const float var = sumsq * (1.f / D_MODEL) - mu * mu;
  const float rstd = rsqrtf(var + LN_EPS);

  #pragma unroll
  for (int u = 0; u < 2; ++u) {
    const int c = u * 256 + lane * 4;
    const float4 g = *(const float4*)(gamma + c);
    const float4 bt = *(const float4*)(beta + c);
    float4 o;
    o.x = (x[u * 4 + 0] - mu) * rstd * g.x + bt.x;
    o.y = (x[u * 4 + 1] - mu) * rstd * g.y + bt.y;
    o.z = (x[u * 4 + 2] - mu) * rstd * g.z + bt.z;
    o.w = (x[u * 4 + 3] - mu) * rstd * g.w + bt.w;
    *(float4*)(out + (size_t)orig * D_MODEL + c) = o;
  }
}

// ---------------------------------------------------------------------------
extern "C" void kernel_launch(void* const* d_in, const int* in_sizes, int n_in,
                              void* d_out, int out_size, void* d_ws, size_t ws_size,
                              hipStream_t stream) {
  const float* positions = (const float*)d_in[0];
  const float* features  = (const float*)d_in[1];
  const float* Wq   = (const float*)d_in[3];
  const float* Wk   = (const float*)d_in[4];
  const float* Wv   = (const float*)d_in[5];
  const float* Wo   = (const float*)d_in[6];
  const float* bo   = (const float*)d_in[7];
  const float* Wpos = (const float*)d_in[8];
  const float* bpos = (const float*)d_in[9];
  const float* temp = (const float*)d_in[10];
  const float* gamma = (const float*)d_in[11];
  const float* beta  = (const float*)d_in[12];

  const int B = 2, N = 4096;
  const int BN = B * N;

  char* w = (char*)d_ws;
  float4* posf4  = (float4*)w;             w += (size_t)BN * sizeof(float4);
  float4* posf4s = (float4*)w;             w += (size_t)BN * sizeof(float4);
  int*    idxb   = (int*)w;                w += (size_t)BN * KNB * sizeof(int);
  int*    permb  = (int*)w;                w += (size_t)BN * sizeof(int);
  int*    histb  = (int*)w;                w += (size_t)B * NBUCK * sizeof(int);
  int*    offb   = (int*)w;                w += (size_t)B * NBUCK * sizeof(int);
  int*    buckb  = (int*)w;                w += (size_t)BN * sizeof(int);
  unsigned short* Abuf = (unsigned short*)w; w += (size_t)BN * 512 * 2;
  unsigned short* BhQKV = (unsigned short*)w; w += (size_t)1536 * 512 * 2;
  unsigned short* BhO = (unsigned short*)w;   w += (size_t)512 * 512 * 2;
  unsigned short* Qb16 = (unsigned short*)w;  w += (size_t)BN * 512 * 2;   // 8 MB
  unsigned short* Kb16 = (unsigned short*)w;  w += (size_t)BN * 512 * 2;   // 8 MB
  unsigned short* Vb16 = (unsigned short*)d_out;   // 8 MB of out; dead before LN
  float* projb = (float*)Qb16;             // 16 MB overlays Qb16+Kb16 (dead)

  hipMemsetAsync(histb, 0, (size_t)B * NBUCK * sizeof(int), stream);
  bucket_kernel<<<(BN + 255) / 256, 256, 0, stream>>>(positions, posf4, histb,
                                                      buckb, BN);
  scan_kernel<<<B, 1024, 0, stream>>>(histb, offb);
  scatter_kernel<<<(BN + 255) / 256, 256, 0, stream>>>(posf4, buckb, offb,
                                                       permb, posf4s, BN);
  knn_kernel<<<BN / 16, 512, 0, stream>>>(posf4s, idxb, N);

  conv_kernel<<<8192, 256, 0, stream>>>(features, permb, Abuf,
                                        Wq, Wk, Wv, Wo, BhQKV, BhO);

  gemm_bf16_kernel<1><<<768, 256, 0, stream>>>(
      Abuf, BhQKV, Qb16, Kb16, Vb16, 12);

  attn_kernel<<<BN / 2, 256, 0, stream>>>(Qb16, Kb16, Vb16, idxb,
                                          posf4s, Wpos, bpos, temp, Abuf,
                                          BN / 2);

  gemm_bf16_kernel<0><<<256, 256, 0, stream>>>(
      Abuf, BhO, projb, projb, projb, 4);

  ln_kernel<<<BN / 4, 256, 0, stream>>>(projb, features, permb, bo, gamma, beta,
                                        (float*)d_out);
}